// Round 2
// baseline (535.565 us; speedup 1.0000x reference)
//
#include <hip/hip_runtime.h>
#include <hip/hip_bf16.h>
#include <math.h>

// Problem constants
#define BATCH 16
#define SEQ   4096
#define HIN   128
#define NST   256
#define HOUT  128
#define CL    32              // chunk length for scan
#define NC    (SEQ/CL)        // 128 chunks
#define ROWS  (BATCH*SEQ)     // 65536
#define BK    16

// ---------------------------------------------------------------- params ----
__global__ __launch_bounds__(256) void k_params(
    const float* __restrict__ nu_log, const float* __restrict__ theta_log,
    const float* __restrict__ gamma_log,
    float* __restrict__ lamre, float* __restrict__ lamim, float* __restrict__ gam) {
  int n = threadIdx.x;
  float lm = expf(-expf(nu_log[n]));
  float th = expf(theta_log[n]);
  lamre[n] = lm * cosf(th);
  lamim[n] = lm * sinf(th);
  gam[n]   = expf(gamma_log[n]);
}

// ------------------------------------------------- Bu = gamma * (u @ B^T) ---
// grid (ROWS/64, NST/64), block 256. 4x4 microtile per thread.
// rows: ty + 16*i (ty in [0,16)), cols: tx + 16*j (tx in [0,16)).
__global__ __launch_bounds__(256) void k_bu(
    const float* __restrict__ u, const float* __restrict__ Bre,
    const float* __restrict__ Bim, const float* __restrict__ gam,
    float* __restrict__ bu_re, float* __restrict__ bu_im) {
  __shared__ float As[64][BK+1];
  __shared__ float Bsr[64][BK+1];
  __shared__ float Bsi[64][BK+1];
  int tid = threadIdx.x;
  int row0 = blockIdx.x * 64;
  int col0 = blockIdx.y * 64;
  int tx = tid & 15, ty = tid >> 4;
  float accr[4][4] = {{0.f}}, acci[4][4] = {{0.f}};
  for (int k0 = 0; k0 < HIN; k0 += BK) {
#pragma unroll
    for (int i = 0; i < 4; ++i) {
      int e = i*256 + tid;
      int r = e >> 4, kk = e & 15;
      As[r][kk]  = u[(row0 + r)*HIN + k0 + kk];
      Bsr[r][kk] = Bre[(col0 + r)*HIN + k0 + kk];
      Bsi[r][kk] = Bim[(col0 + r)*HIN + k0 + kk];
    }
    __syncthreads();
#pragma unroll
    for (int kk = 0; kk < BK; ++kk) {
      float a[4], br[4], bi[4];
#pragma unroll
      for (int i = 0; i < 4; ++i) a[i] = As[ty + 16*i][kk];
#pragma unroll
      for (int j = 0; j < 4; ++j) { br[j] = Bsr[tx + 16*j][kk]; bi[j] = Bsi[tx + 16*j][kk]; }
#pragma unroll
      for (int i = 0; i < 4; ++i)
#pragma unroll
        for (int j = 0; j < 4; ++j) { accr[i][j] += a[i]*br[j]; acci[i][j] += a[i]*bi[j]; }
    }
    __syncthreads();
  }
#pragma unroll
  for (int j = 0; j < 4; ++j) {
    int c = col0 + tx + 16*j;
    float g = gam[c];
#pragma unroll
    for (int i = 0; i < 4; ++i) {
      int r = row0 + ty + 16*i;
      bu_re[r*NST + c] = accr[i][j]*g;
      bu_im[r*NST + c] = acci[i][j]*g;
    }
  }
}

// --------------------------------------------------------- uD = u @ D^T ----
// grid (ROWS/64, HOUT/64), block 256.
__global__ __launch_bounds__(256) void k_ud(
    const float* __restrict__ u, const float* __restrict__ Dm,
    float* __restrict__ uD) {
  __shared__ float As[64][BK+1];
  __shared__ float Ds[64][BK+1];
  int tid = threadIdx.x;
  int row0 = blockIdx.x * 64;
  int col0 = blockIdx.y * 64;
  int tx = tid & 15, ty = tid >> 4;
  float acc[4][4] = {{0.f}};
  for (int k0 = 0; k0 < HIN; k0 += BK) {
#pragma unroll
    for (int i = 0; i < 4; ++i) {
      int e = i*256 + tid;
      int r = e >> 4, kk = e & 15;
      As[r][kk] = u[(row0 + r)*HIN + k0 + kk];
      Ds[r][kk] = Dm[(col0 + r)*HIN + k0 + kk];
    }
    __syncthreads();
#pragma unroll
    for (int kk = 0; kk < BK; ++kk) {
      float a[4], d[4];
#pragma unroll
      for (int i = 0; i < 4; ++i) a[i] = As[ty + 16*i][kk];
#pragma unroll
      for (int j = 0; j < 4; ++j) d[j] = Ds[tx + 16*j][kk];
#pragma unroll
      for (int i = 0; i < 4; ++i)
#pragma unroll
        for (int j = 0; j < 4; ++j) acc[i][j] += a[i]*d[j];
    }
    __syncthreads();
  }
#pragma unroll
  for (int j = 0; j < 4; ++j) {
    int c = col0 + tx + 16*j;
#pragma unroll
    for (int i = 0; i < 4; ++i) {
      int r = row0 + ty + 16*i;
      uD[r*HOUT + c] = acc[i][j];
    }
  }
}

// ------------------------------------------- chunk carries (Horner) --------
// grid BATCH*NC, block 256 (one thread per state n)
__global__ __launch_bounds__(256) void k_carry(
    const float* __restrict__ bu_re, const float* __restrict__ bu_im,
    const float* __restrict__ lamre, const float* __restrict__ lamim,
    float* __restrict__ S_re, float* __restrict__ S_im) {
  int blk = blockIdx.x;
  int b = blk >> 7, c = blk & (NC-1);
  int n = threadIdx.x;
  float lr = lamre[n], li = lamim[n];
  float sr = 0.f, si = 0.f;
  long base = ((long)(b*SEQ + c*CL))*NST + n;
  for (int t = 0; t < CL; ++t) {
    float br = bu_re[base], bi = bu_im[base];
    float nr = lr*sr - li*si + br;
    float ni = lr*si + li*sr + bi;
    sr = nr; si = ni; base += NST;
  }
  int idx = (b*NC + c)*NST + n;
  S_re[idx] = sr; S_im[idx] = si;
}

// ------------------------------- scan carries across chunks -> X0 ----------
// grid BATCH, block 256
__global__ __launch_bounds__(256) void k_chunkscan(
    const float* __restrict__ S_re, const float* __restrict__ S_im,
    const float* __restrict__ lamre, const float* __restrict__ lamim,
    float* __restrict__ X0_re, float* __restrict__ X0_im) {
  int b = blockIdx.x;
  int n = threadIdx.x;
  float ar = lamre[n], ai = lamim[n];
  // lam^CL = lam^32: 5 complex squarings
#pragma unroll
  for (int s = 0; s < 5; ++s) {
    float nr = ar*ar - ai*ai;
    float ni = 2.f*ar*ai;
    ar = nr; ai = ni;
  }
  float cr = 0.f, ci = 0.f;
  for (int c = 0; c < NC; ++c) {
    int idx = (b*NC + c)*NST + n;
    X0_re[idx] = cr; X0_im[idx] = ci;
    float nr = ar*cr - ai*ci + S_re[idx];
    float ni = ar*ci + ai*cr + S_im[idx];
    cr = nr; ci = ni;
  }
}

// ---------------- fused: local scan (LDS) + output projection --------------
// grid BATCH*NC, block 256.
// LDS: pre bf16 [32][256] x2 = 32 KB, C tiles bf16 [32][130] x2 = 16.6 KB
// total ~49 KB -> 3 blocks/CU, safely under the 64 KB per-WG limit.
__global__ __launch_bounds__(256) void k_out(
    const float* __restrict__ bu_re, const float* __restrict__ bu_im,
    const float* __restrict__ X0_re, const float* __restrict__ X0_im,
    const float* __restrict__ lamre, const float* __restrict__ lamim,
    const float* __restrict__ Cre, const float* __restrict__ Cim,
    const float* __restrict__ uD, float* __restrict__ y) {
  __shared__ __hip_bfloat16 pre_re[CL][NST];
  __shared__ __hip_bfloat16 pre_im[CL][NST];
  __shared__ __hip_bfloat16 csr[32][HOUT+2];
  __shared__ __hip_bfloat16 csi[32][HOUT+2];
  int blk = blockIdx.x;
  int b = blk >> 7, c = blk & (NC-1);
  int tid = threadIdx.x;
  int t0 = c*CL;
  // phase 1: local scan; write pre-states (x entering step t) to LDS as bf16
  {
    int n = tid;
    float lr = lamre[n], li = lamim[n];
    int idx = (b*NC + c)*NST + n;
    float xr = X0_re[idx], xi = X0_im[idx];
    long base = ((long)(b*SEQ + t0))*NST + n;
#pragma unroll 4
    for (int t = 0; t < CL; ++t) {
      pre_re[t][n] = __float2bfloat16(xr);
      pre_im[t][n] = __float2bfloat16(xi);
      float br = bu_re[base], bi = bu_im[base];
      float nr = lr*xr - li*xi + br;
      float ni = lr*xi + li*xr + bi;
      xr = nr; xi = ni; base += NST;
    }
  }
  __syncthreads();
  // phase 2: y[t,o] = uD[t,o] + sum_n pre_re[n,t]*C_re[o,n] - pre_im[n,t]*C_im[o,n]
  int og = tid & 31, tg = tid >> 5;   // 32 o-groups x 8 t-groups
  float acc[4][4];
#pragma unroll
  for (int i = 0; i < 4; ++i) {
    int t = tg + 8*i;
#pragma unroll
    for (int j = 0; j < 4; ++j) {
      int o = og + 32*j;
      acc[i][j] = uD[((long)(b*SEQ + t0 + t))*HOUT + o];
    }
  }
  for (int nb = 0; nb < 8; ++nb) {
    // stage C[:, nb*32 .. nb*32+32) as cs[nn][o], bf16
#pragma unroll
    for (int it = 0; it < 16; ++it) {
      int e = it*256 + tid;
      int nn = e & 31, o = e >> 5;
      csr[nn][o] = __float2bfloat16(Cre[o*NST + nb*32 + nn]);
      csi[nn][o] = __float2bfloat16(Cim[o*NST + nb*32 + nn]);
    }
    __syncthreads();
    for (int nn = 0; nn < 32; ++nn) {
      int n = nb*32 + nn;
      float pr[4], pi[4], cr[4], ci[4];
#pragma unroll
      for (int i = 0; i < 4; ++i) {
        pr[i] = __bfloat162float(pre_re[tg+8*i][n]);
        pi[i] = __bfloat162float(pre_im[tg+8*i][n]);
      }
#pragma unroll
      for (int j = 0; j < 4; ++j) {
        cr[j] = __bfloat162float(csr[nn][og+32*j]);
        ci[j] = __bfloat162float(csi[nn][og+32*j]);
      }
#pragma unroll
      for (int i = 0; i < 4; ++i)
#pragma unroll
        for (int j = 0; j < 4; ++j) acc[i][j] += pr[i]*cr[j] - pi[i]*ci[j];
    }
    __syncthreads();
  }
#pragma unroll
  for (int i = 0; i < 4; ++i) {
    int t = t0 + tg + 8*i;
#pragma unroll
    for (int j = 0; j < 4; ++j) {
      int o = og + 32*j;
      y[((long)(b*SEQ + t))*HOUT + o] = acc[i][j];
    }
  }
}

// --------------------------------------------------------------------------
extern "C" void kernel_launch(void* const* d_in, const int* in_sizes, int n_in,
                              void* d_out, int out_size, void* d_ws, size_t ws_size,
                              hipStream_t stream) {
  const float* u         = (const float*)d_in[0];
  const float* nu_log    = (const float*)d_in[1];
  const float* theta_log = (const float*)d_in[2];
  const float* gamma_log = (const float*)d_in[3];
  const float* B_re      = (const float*)d_in[4];
  const float* B_im      = (const float*)d_in[5];
  const float* C_re      = (const float*)d_in[6];
  const float* C_im      = (const float*)d_in[7];
  const float* Dm        = (const float*)d_in[8];
  float* y  = (float*)d_out;
  float* ws = (float*)d_ws;

  // workspace layout (floats)
  float* lamre = ws;               // 256
  float* lamim = ws + 256;         // 256
  float* gam   = ws + 512;         // 256
  float* bu_re = ws + 1024;                    // 16,777,216
  float* bu_im = bu_re + (long)ROWS*NST;       // 16,777,216
  float* uD    = bu_im + (long)ROWS*NST;       // 8,388,608
  float* S_re  = uD    + (long)ROWS*HOUT;      // 524,288
  float* S_im  = S_re  + (long)BATCH*NC*NST;
  float* X0_re = S_im  + (long)BATCH*NC*NST;
  float* X0_im = X0_re + (long)BATCH*NC*NST;

  k_params<<<1, 256, 0, stream>>>(nu_log, theta_log, gamma_log, lamre, lamim, gam);
  k_bu<<<dim3(ROWS/64, NST/64), 256, 0, stream>>>(u, B_re, B_im, gam, bu_re, bu_im);
  k_ud<<<dim3(ROWS/64, HOUT/64), 256, 0, stream>>>(u, Dm, uD);
  k_carry<<<BATCH*NC, 256, 0, stream>>>(bu_re, bu_im, lamre, lamim, S_re, S_im);
  k_chunkscan<<<BATCH, 256, 0, stream>>>(S_re, S_im, lamre, lamim, X0_re, X0_im);
  k_out<<<BATCH*NC, 256, 0, stream>>>(bu_re, bu_im, X0_re, X0_im, lamre, lamim,
                                      C_re, C_im, uD, y);
}

// Round 4
// 254.803 us; speedup vs baseline: 2.1019x; 2.1019x over previous
//
#include <hip/hip_runtime.h>
#include <math.h>

// Problem constants
#define BATCH 16
#define SEQ   4096
#define HIN   128
#define NST   256
#define HOUT  128
#define CL    32              // chunk length for scan
#define NC    (SEQ/CL)        // 128 chunks
#define ROWS  (BATCH*SEQ)     // 65536
#define KTOT  640             // 256 re + 256 im + 128 u (output GEMM K)
#define NBU   512             // bu row width: re[0:256) im[256:512)

typedef __attribute__((ext_vector_type(8))) short short8;
typedef __attribute__((ext_vector_type(4))) float f32x4;

__device__ inline unsigned short f2bf(float f) {
  union { float f; unsigned u; } v; v.f = f;
  unsigned r = v.u + 0x7FFFu + ((v.u >> 16) & 1u);   // RNE
  return (unsigned short)(r >> 16);
}
__device__ inline float bf2f(unsigned short s) {
  union { unsigned u; float f; } v; v.u = ((unsigned)s) << 16;
  return v.f;
}

// ------------------------------------------------------------- prep --------
// lam, W_b = gamma*[B_re;B_im] bf16 [512][128], W = [C_re | -C_im | D] bf16 [128][640]
__global__ __launch_bounds__(256) void k_prep(
    const float* __restrict__ nu_log, const float* __restrict__ theta_log,
    const float* __restrict__ gamma_log,
    const float* __restrict__ Bre, const float* __restrict__ Bim,
    const float* __restrict__ Cre, const float* __restrict__ Cim,
    const float* __restrict__ Dm,
    float* __restrict__ lamre, float* __restrict__ lamim,
    unsigned short* __restrict__ Wb, unsigned short* __restrict__ W) {
  int idx = blockIdx.x*256 + threadIdx.x;
  if (idx < NST) {
    float lm = expf(-expf(nu_log[idx]));
    float th = expf(theta_log[idx]);
    lamre[idx] = lm * cosf(th);
    lamim[idx] = lm * sinf(th);
  }
  if (idx < 512*HIN) {
    int n = idx >> 7, h = idx & 127;
    float g = expf(gamma_log[n & 255]);
    float v = (n < NST) ? Bre[n*HIN + h] : Bim[(n-NST)*HIN + h];
    Wb[idx] = f2bf(g * v);
  }
  if (idx < HOUT*KTOT) {
    int o = idx / KTOT, k = idx - o*KTOT;
    float v;
    if (k < NST)        v =  Cre[o*NST + k];
    else if (k < 2*NST) v = -Cim[o*NST + (k - NST)];
    else                v =  Dm[o*HIN + (k - 2*NST)];
    W[idx] = f2bf(v);
  }
}

// ------------------------------------------------------- u -> bf16 cast ----
__global__ __launch_bounds__(256) void k_cast(
    const float* __restrict__ u, unsigned short* __restrict__ ubf) {
  size_t i = (size_t)(blockIdx.x*256 + threadIdx.x) * 4;
  float4 v = *(const float4*)(u + i);
  ushort4 o;
  o.x = f2bf(v.x); o.y = f2bf(v.y); o.z = f2bf(v.z); o.w = f2bf(v.w);
  *(ushort4*)(ubf + i) = o;
}

// ----------------------------------- bu = ubf @ Wb^T  (MFMA bf16 GEMM) -----
// grid (ROWS/128, 512/128), block 256. 128x128 tile, K=128 in 2 stages of 64.
// bu stored FP32 (bisect: bf16 bu in the scan path was the prime error suspect)
#define BUP 8   // LDS pad (shorts)
__global__ __launch_bounds__(256) void k_bu(
    const unsigned short* __restrict__ ubf, const unsigned short* __restrict__ Wb,
    float* __restrict__ bu) {
  __shared__ unsigned short Asl[128][64+BUP];
  __shared__ unsigned short Bsl[128][64+BUP];
  int tid = threadIdx.x;
  int row0 = blockIdx.x * 128;
  int col0 = blockIdx.y * 128;
  int wid = tid >> 6, lane = tid & 63;
  int lm = lane & 15, lq = lane >> 4;
  int m0 = (wid >> 1) * 64, n0 = (wid & 1) * 64;
  f32x4 acc[4][4];
#pragma unroll
  for (int i = 0; i < 4; ++i)
#pragma unroll
    for (int j = 0; j < 4; ++j) acc[i][j] = (f32x4)0.f;
  for (int s = 0; s < 2; ++s) {
#pragma unroll
    for (int cc = 0; cc < 4; ++cc) {
      int ch = cc*256 + tid;               // 0..1023 chunks of 8 shorts
      int r = ch >> 3, h0 = (ch & 7) * 8;
      *(short8*)&Asl[r][h0] = *(const short8*)&ubf[(size_t)(row0 + r)*HIN + s*64 + h0];
      *(short8*)&Bsl[r][h0] = *(const short8*)&Wb [(size_t)(col0 + r)*HIN + s*64 + h0];
    }
    __syncthreads();
#pragma unroll
    for (int ks = 0; ks < 2; ++ks) {
      int k0 = ks*32 + lq*8;
      short8 a[4], b[4];
#pragma unroll
      for (int i = 0; i < 4; ++i) a[i] = *(const short8*)&Asl[m0 + i*16 + lm][k0];
#pragma unroll
      for (int j = 0; j < 4; ++j) b[j] = *(const short8*)&Bsl[n0 + j*16 + lm][k0];
#pragma unroll
      for (int i = 0; i < 4; ++i)
#pragma unroll
        for (int j = 0; j < 4; ++j)
          acc[i][j] = __builtin_amdgcn_mfma_f32_16x16x32_bf16(a[i], b[j], acc[i][j], 0, 0, 0);
    }
    __syncthreads();
  }
#pragma unroll
  for (int i = 0; i < 4; ++i)
#pragma unroll
    for (int j = 0; j < 4; ++j)
#pragma unroll
      for (int r = 0; r < 4; ++r)
        bu[(size_t)(row0 + m0 + i*16 + lq*4 + r)*NBU + col0 + n0 + j*16 + lm] =
            acc[i][j][r];
}

// ------------------------------------------- chunk carries (Horner) --------
// grid BATCH*NC, block 256 (one thread per state n)
__global__ __launch_bounds__(256) void k_carry(
    const float* __restrict__ bu,
    const float* __restrict__ lamre, const float* __restrict__ lamim,
    float* __restrict__ S_re, float* __restrict__ S_im) {
  int blk = blockIdx.x;
  int b = blk >> 7, c = blk & (NC-1);
  int n = threadIdx.x;
  float lr = lamre[n], li = lamim[n];
  float sr = 0.f, si = 0.f;
  size_t base = (size_t)(b*SEQ + c*CL) * NBU;
  for (int t = 0; t < CL; ++t) {
    float br = bu[base + n];
    float bi = bu[base + NST + n];
    float nr = lr*sr - li*si + br;
    float ni = lr*si + li*sr + bi;
    sr = nr; si = ni; base += NBU;
  }
  int idx = (b*NC + c)*NST + n;
  S_re[idx] = sr; S_im[idx] = si;
}

// ---------------- two-level scan of chunk carries -> X0 --------------------
// level 1: carries over groups of 16 chunks. grid BATCH*8, block 256.
__global__ __launch_bounds__(256) void k_carry2(
    const float* __restrict__ S_re, const float* __restrict__ S_im,
    const float* __restrict__ lamre, const float* __restrict__ lamim,
    float* __restrict__ G_re, float* __restrict__ G_im) {
  int blk = blockIdx.x;
  int b = blk >> 3, g = blk & 7;
  int n = threadIdx.x;
  float ar = lamre[n], ai = lamim[n];
#pragma unroll
  for (int s = 0; s < 5; ++s) { float nr = ar*ar - ai*ai, ni = 2.f*ar*ai; ar = nr; ai = ni; } // lam^32
  float tr = 0.f, ti = 0.f;
  for (int c = g*16; c < g*16 + 16; ++c) {
    int idx = (b*NC + c)*NST + n;
    float nr = ar*tr - ai*ti + S_re[idx];
    float ni = ar*ti + ai*tr + S_im[idx];
    tr = nr; ti = ni;
  }
  int gi = (b*8 + g)*NST + n;
  G_re[gi] = tr; G_im[gi] = ti;
}

// level 2: each (b,g,n) thread builds its group prefix then emits X0 per chunk.
__global__ __launch_bounds__(256) void k_final(
    const float* __restrict__ S_re, const float* __restrict__ S_im,
    const float* __restrict__ G_re, const float* __restrict__ G_im,
    const float* __restrict__ lamre, const float* __restrict__ lamim,
    float* __restrict__ X0_re, float* __restrict__ X0_im) {
  int blk = blockIdx.x;
  int b = blk >> 3, g = blk & 7;
  int n = threadIdx.x;
  float ar = lamre[n], ai = lamim[n];
#pragma unroll
  for (int s = 0; s < 5; ++s) { float nr = ar*ar - ai*ai, ni = 2.f*ar*ai; ar = nr; ai = ni; } // lam^32
  float a5r = ar, a5i = ai;
#pragma unroll
  for (int s = 0; s < 4; ++s) { float nr = a5r*a5r - a5i*a5i, ni = 2.f*a5r*a5i; a5r = nr; a5i = ni; } // lam^512
  float pr = 0.f, pi = 0.f;
  for (int j = 0; j < g; ++j) {
    int gi = (b*8 + j)*NST + n;
    float nr = a5r*pr - a5i*pi + G_re[gi];
    float ni = a5r*pi + a5i*pr + G_im[gi];
    pr = nr; pi = ni;
  }
  float xr = pr, xi = pi;
  for (int c = g*16; c < g*16 + 16; ++c) {
    int idx = (b*NC + c)*NST + n;
    X0_re[idx] = xr; X0_im[idx] = xi;
    float nr = ar*xr - ai*xi + S_re[idx];
    float ni = ar*xi + ai*xr + S_im[idx];
    xr = nr; xi = ni;
  }
}

// ---------------- fused: local scan (LDS) + MFMA output projection ---------
// grid BATCH*NC, block 256.
// LDS: pre[32][648] shorts = 40.5 KB (rows: re[0:256) im[256:512) u[512:640))
#define PRE_STRIDE (KTOT + 8)   // 648 shorts
__global__ __launch_bounds__(256) void k_out(
    const float* __restrict__ bu, const unsigned short* __restrict__ ubf,
    const float* __restrict__ X0_re, const float* __restrict__ X0_im,
    const float* __restrict__ lamre, const float* __restrict__ lamim,
    const unsigned short* __restrict__ W, float* __restrict__ y) {
  __shared__ unsigned short pre[CL][PRE_STRIDE];
  int blk = blockIdx.x;
  int b = blk >> 7, c = blk & (NC-1);
  int tid = threadIdx.x;
  int t0 = c*CL;
  // stage u tile (32x128 bf16) into pre[t][512+..]
  {
    const unsigned short* usrc = ubf + (size_t)(b*SEQ + t0)*HIN;
#pragma unroll
    for (int c2 = tid; c2 < 512; c2 += 256) {
      int t = c2 >> 4, h0 = (c2 & 15) * 8;
      *(short8*)&pre[t][2*NST + h0] = *(const short8*)&usrc[t*HIN + h0];
    }
  }
  // local scan: write pre-states x_{t-1} (bf16) into pre[t][n], pre[t][256+n]
  {
    int n = tid;
    float lr = lamre[n], li = lamim[n];
    int idx = (b*NC + c)*NST + n;
    float xr = X0_re[idx], xi = X0_im[idx];
    size_t base = (size_t)(b*SEQ + t0) * NBU;
    for (int t = 0; t < CL; ++t) {
      pre[t][n]       = f2bf(xr);
      pre[t][NST + n] = f2bf(xi);
      float br = bu[base + n];
      float bi = bu[base + NST + n];
      float nr = lr*xr - li*xi + br;
      float ni = lr*xi + li*xr + bi;
      xr = nr; xi = ni; base += NBU;
    }
  }
  __syncthreads();
  // MFMA: y[32 t][128 o] = pre[32][640] @ W[128][640]^T
  int wid = tid >> 6, lane = tid & 63;
  int lm = lane & 15, lq = lane >> 4;
  int tt = wid >> 1, oh = wid & 1;          // 2 t-tiles x 2 o-halves
  f32x4 acc[4];
#pragma unroll
  for (int j = 0; j < 4; ++j) acc[j] = (f32x4)0.f;
  for (int s = 0; s < 20; ++s) {
    int k0 = s*32 + lq*8;
    short8 a = *(const short8*)&pre[tt*16 + lm][k0];
#pragma unroll
    for (int j = 0; j < 4; ++j) {
      short8 bf = *(const short8*)&W[(size_t)(oh*64 + j*16 + lm)*KTOT + k0];
      acc[j] = __builtin_amdgcn_mfma_f32_16x16x32_bf16(a, bf, acc[j], 0, 0, 0);
    }
  }
#pragma unroll
  for (int j = 0; j < 4; ++j)
#pragma unroll
    for (int r = 0; r < 4; ++r)
      y[(size_t)(b*SEQ + t0 + tt*16 + lq*4 + r)*HOUT + oh*64 + j*16 + lm] = acc[j][r];
}

// --------------------------------------------------------------------------
extern "C" void kernel_launch(void* const* d_in, const int* in_sizes, int n_in,
                              void* d_out, int out_size, void* d_ws, size_t ws_size,
                              hipStream_t stream) {
  const float* u         = (const float*)d_in[0];
  const float* nu_log    = (const float*)d_in[1];
  const float* theta_log = (const float*)d_in[2];
  const float* gamma_log = (const float*)d_in[3];
  const float* B_re      = (const float*)d_in[4];
  const float* B_im      = (const float*)d_in[5];
  const float* C_re      = (const float*)d_in[6];
  const float* C_im      = (const float*)d_in[7];
  const float* Dm        = (const float*)d_in[8];
  float* y = (float*)d_out;
  char* ws = (char*)d_ws;

  // workspace layout (byte offsets)
  float*          lamre = (float*)(ws);                      // 256 f
  float*          lamim = (float*)(ws + 1024);               // 256 f
  unsigned short* ubf   = (unsigned short*)(ws + 4096);              // 16 MB
  unsigned short* Wb    = (unsigned short*)(ws + 4096 + 16777216);   // 128 KB
  unsigned short* W     = (unsigned short*)(ws + 4096 + 16777216 + 131072); // 160 KB
  float*          bu    = (float*)(ws + 4096 + 16777216 + 131072 + 163840); // 128 MB f32
  char* p2 = ws + 4096 + 16777216 + 131072 + 163840 + (size_t)ROWS*NBU*4;
  float* S_re  = (float*)(p2);
  float* S_im  = (float*)(p2 + 2097152);
  float* G_re  = (float*)(p2 + 2*2097152);
  float* G_im  = (float*)(p2 + 2*2097152 + 131072);
  float* X0_re = (float*)(p2 + 2*2097152 + 2*131072);
  float* X0_im = (float*)(p2 + 3*2097152 + 2*131072);

  k_prep<<<320, 256, 0, stream>>>(nu_log, theta_log, gamma_log, B_re, B_im,
                                  C_re, C_im, Dm, lamre, lamim, Wb, W);
  k_cast<<<(ROWS*HIN)/1024, 256, 0, stream>>>(u, ubf);
  k_bu<<<dim3(ROWS/128, 4), 256, 0, stream>>>(ubf, Wb, bu);
  k_carry<<<BATCH*NC, 256, 0, stream>>>(bu, lamre, lamim, S_re, S_im);
  k_carry2<<<BATCH*8, 256, 0, stream>>>(S_re, S_im, lamre, lamim, G_re, G_im);
  k_final<<<BATCH*8, 256, 0, stream>>>(S_re, S_im, G_re, G_im, lamre, lamim,
                                       X0_re, X0_im);
  k_out<<<BATCH*NC, 256, 0, stream>>>(bu, ubf, X0_re, X0_im, lamre, lamim, W, y);
}

// Round 5
// 238.372 us; speedup vs baseline: 2.2468x; 1.0689x over previous
//
#include <hip/hip_runtime.h>
#include <math.h>

// Problem constants
#define BATCH 16
#define SEQ   4096
#define HIN   128
#define NST   256
#define HOUT  128
#define CL    32              // chunk length for scan
#define NC    (SEQ/CL)        // 128 chunks
#define ROWS  (BATCH*SEQ)     // 65536
#define KTOT  640             // 256 re + 256 im + 128 u (output GEMM K)
#define NBU   512             // bu row width (permuted): g*128 + [re 64 | im 64]

typedef __attribute__((ext_vector_type(8))) short short8;
typedef __attribute__((ext_vector_type(4))) float f32x4;

__device__ inline unsigned short f2bf(float f) {
  union { float f; unsigned u; } v; v.f = f;
  unsigned r = v.u + 0x7FFFu + ((v.u >> 16) & 1u);   // RNE
  return (unsigned short)(r >> 16);
}
__device__ inline float bf2f(unsigned short s) {
  union { unsigned u; float f; } v; v.u = ((unsigned)s) << 16;
  return v.f;
}

// ------------------------------------------------------------- prep --------
// Wb rows PERMUTED: row r: g=r>>7, w=r&127; n = g*64 + (w&63);
//   w<64 -> gamma*B_re[n], else gamma*B_im[n].
// W = [C_re | -C_im | D] bf16 [128][640] (canonical n order).
__global__ __launch_bounds__(256) void k_prep(
    const float* __restrict__ nu_log, const float* __restrict__ theta_log,
    const float* __restrict__ gamma_log,
    const float* __restrict__ Bre, const float* __restrict__ Bim,
    const float* __restrict__ Cre, const float* __restrict__ Cim,
    const float* __restrict__ Dm,
    float* __restrict__ lamre, float* __restrict__ lamim,
    unsigned short* __restrict__ Wb, unsigned short* __restrict__ W) {
  int idx = blockIdx.x*256 + threadIdx.x;
  if (idx < NST) {
    float lm = expf(-expf(nu_log[idx]));
    float th = expf(theta_log[idx]);
    lamre[idx] = lm * cosf(th);
    lamim[idx] = lm * sinf(th);
  }
  if (idx < 512*HIN) {
    int r = idx >> 7, h = idx & 127;
    int g = r >> 7;  // wait: r in [0,512) -> g = r>>7 in [0,4)
    int w = r & 127;
    int n = g*64 + (w & 63);
    float gm = expf(gamma_log[n]);
    float v = (w < 64) ? Bre[n*HIN + h] : Bim[n*HIN + h];
    Wb[idx] = f2bf(gm * v);
  }
  if (idx < HOUT*KTOT) {
    int o = idx / KTOT, k = idx - o*KTOT;
    float v;
    if (k < NST)        v =  Cre[o*NST + k];
    else if (k < 2*NST) v = -Cim[o*NST + (k - NST)];
    else                v =  Dm[o*HIN + (k - 2*NST)];
    W[idx] = f2bf(v);
  }
}

// ------------------------------------------------------- u -> bf16 cast ----
__global__ __launch_bounds__(256) void k_cast(
    const float* __restrict__ u, unsigned short* __restrict__ ubf) {
  size_t i = (size_t)(blockIdx.x*256 + threadIdx.x) * 4;
  float4 v = *(const float4*)(u + i);
  ushort4 o;
  o.x = f2bf(v.x); o.y = f2bf(v.y); o.z = f2bf(v.z); o.w = f2bf(v.w);
  *(ushort4*)(ubf + i) = o;
}

// ------------- bu GEMM (MFMA) + fused chunk-carry epilogue -----------------
// grid (ROWS/128, 4), block 256. Tile 128 t-rows x 128 cols (64 complex n).
// Stores bu bf16 (for k_out local re-scan) and S_re/S_im f32 carries.
union SharedU {
  struct { unsigned short A[128][72], B[128][72]; } s1;   // 36.9 KB staging
  struct { float stg[2][32][132]; } s2;                   // 33.8 KB carry stage
};
__global__ __launch_bounds__(256) void k_bu(
    const unsigned short* __restrict__ ubf, const unsigned short* __restrict__ Wb,
    const float* __restrict__ lamre, const float* __restrict__ lamim,
    unsigned short* __restrict__ bu16,
    float* __restrict__ S_re, float* __restrict__ S_im) {
  __shared__ SharedU sh;
  int tid = threadIdx.x;
  int row0 = blockIdx.x * 128;
  int g    = blockIdx.y;
  int col0 = g * 128;
  int wid = tid >> 6, lane = tid & 63;
  int lm = lane & 15, lq = lane >> 4;
  int m0 = (wid >> 1) * 64, n0 = (wid & 1) * 64;
  f32x4 acc[4][4];
#pragma unroll
  for (int i = 0; i < 4; ++i)
#pragma unroll
    for (int j = 0; j < 4; ++j) acc[i][j] = (f32x4)0.f;
  for (int s = 0; s < 2; ++s) {
#pragma unroll
    for (int cc = 0; cc < 4; ++cc) {
      int ch = cc*256 + tid;               // 1024 chunks of 8 shorts
      int r = ch >> 3, h0 = (ch & 7) * 8;
      *(short8*)&sh.s1.A[r][h0] = *(const short8*)&ubf[(size_t)(row0 + r)*HIN + s*64 + h0];
      *(short8*)&sh.s1.B[r][h0] = *(const short8*)&Wb [(size_t)(col0 + r)*HIN + s*64 + h0];
    }
    __syncthreads();
#pragma unroll
    for (int ks = 0; ks < 2; ++ks) {
      int k0 = ks*32 + lq*8;
      short8 a[4], b[4];
#pragma unroll
      for (int i = 0; i < 4; ++i) a[i] = *(const short8*)&sh.s1.A[m0 + i*16 + lm][k0];
#pragma unroll
      for (int j = 0; j < 4; ++j) b[j] = *(const short8*)&sh.s1.B[n0 + j*16 + lm][k0];
#pragma unroll
      for (int i = 0; i < 4; ++i)
#pragma unroll
        for (int j = 0; j < 4; ++j)
          acc[i][j] = __builtin_amdgcn_mfma_f32_16x16x32_bf16(a[i], b[j], acc[i][j], 0, 0, 0);
    }
    __syncthreads();
  }
  // epilogue A: bf16 bu store (permuted col layout, matches Wb rows)
#pragma unroll
  for (int i = 0; i < 4; ++i)
#pragma unroll
    for (int j = 0; j < 4; ++j)
#pragma unroll
      for (int r = 0; r < 4; ++r)
        bu16[(size_t)(row0 + m0 + i*16 + lq*4 + r)*NBU + col0 + n0 + j*16 + lm] =
            f2bf(acc[i][j][r]);
  // epilogue B: f32 carries via LDS. rows 0-63 (waves 0,1) chunks p,p+1 off 0;
  // rows 64-127 (waves 2,3) chunks p+2.
  int b = row0 >> 12;                 // SEQ = 4096
  int cbase = (row0 & 4095) >> 5;     // /CL
  for (int p = 0; p < 2; ++p) {
    __syncthreads();
#pragma unroll
    for (int ii = 0; ii < 2; ++ii) {
      int i = 2*p + ii;
#pragma unroll
      for (int j = 0; j < 4; ++j)
#pragma unroll
        for (int r = 0; r < 4; ++r) {
          int trow = ii*16 + lq*4 + r;              // 0..31 within chunk
          sh.s2.stg[wid >> 1][trow][n0 + j*16 + lm] = acc[i][j][r];
        }
    }
    __syncthreads();
    if (tid < 128) {
      int buf = tid >> 6, n = tid & 63;
      int ng = g*64 + n;
      float lr = lamre[ng], li = lamim[ng];
      float sr = 0.f, si = 0.f;
#pragma unroll
      for (int t = 0; t < 32; ++t) {
        float br = sh.s2.stg[buf][t][n];
        float bi = sh.s2.stg[buf][t][64 + n];
        float nr = lr*sr - li*si + br;
        float ni = lr*si + li*sr + bi;
        sr = nr; si = ni;
      }
      int c = cbase + p + 2*buf;
      int idx = (b*NC + c)*NST + ng;
      S_re[idx] = sr; S_im[idx] = si;
    }
  }
}

// ---------------- two-level scan of chunk carries -> X0 --------------------
// level 1: carries over groups of 16 chunks. grid BATCH*8, block 256.
__global__ __launch_bounds__(256) void k_carry2(
    const float* __restrict__ S_re, const float* __restrict__ S_im,
    const float* __restrict__ lamre, const float* __restrict__ lamim,
    float* __restrict__ G_re, float* __restrict__ G_im) {
  int blk = blockIdx.x;
  int b = blk >> 3, g = blk & 7;
  int n = threadIdx.x;
  float ar = lamre[n], ai = lamim[n];
#pragma unroll
  for (int s = 0; s < 5; ++s) { float nr = ar*ar - ai*ai, ni = 2.f*ar*ai; ar = nr; ai = ni; } // lam^32
  float tr = 0.f, ti = 0.f;
#pragma unroll
  for (int cc = 0; cc < 16; ++cc) {
    int idx = (b*NC + g*16 + cc)*NST + n;
    float nr = ar*tr - ai*ti + S_re[idx];
    float ni = ar*ti + ai*tr + S_im[idx];
    tr = nr; ti = ni;
  }
  int gi = (b*8 + g)*NST + n;
  G_re[gi] = tr; G_im[gi] = ti;
}

// level 2: group prefix then per-chunk X0. grid BATCH*8, block 256.
__global__ __launch_bounds__(256) void k_final(
    const float* __restrict__ S_re, const float* __restrict__ S_im,
    const float* __restrict__ G_re, const float* __restrict__ G_im,
    const float* __restrict__ lamre, const float* __restrict__ lamim,
    float* __restrict__ X0_re, float* __restrict__ X0_im) {
  int blk = blockIdx.x;
  int b = blk >> 3, g = blk & 7;
  int n = threadIdx.x;
  float ar = lamre[n], ai = lamim[n];
#pragma unroll
  for (int s = 0; s < 5; ++s) { float nr = ar*ar - ai*ai, ni = 2.f*ar*ai; ar = nr; ai = ni; } // lam^32
  float a5r = ar, a5i = ai;
#pragma unroll
  for (int s = 0; s < 4; ++s) { float nr = a5r*a5r - a5i*a5i, ni = 2.f*a5r*a5i; a5r = nr; a5i = ni; } // lam^512
  float pr = 0.f, pi = 0.f;
  for (int j = 0; j < g; ++j) {
    int gi = (b*8 + j)*NST + n;
    float nr = a5r*pr - a5i*pi + G_re[gi];
    float ni = a5r*pi + a5i*pr + G_im[gi];
    pr = nr; pi = ni;
  }
  float xr = pr, xi = pi;
#pragma unroll
  for (int cc = 0; cc < 16; ++cc) {
    int idx = (b*NC + g*16 + cc)*NST + n;
    X0_re[idx] = xr; X0_im[idx] = xi;
    float nr = ar*xr - ai*xi + S_re[idx];
    float ni = ar*xi + ai*xr + S_im[idx];
    xr = nr; xi = ni;
  }
}

// ---------------- fused: local scan (LDS) + MFMA output projection ---------
// grid BATCH*NC, block 256. LDS: pre[32][648] shorts = 40.5 KB.
#define PRE_STRIDE (KTOT + 8)
__global__ __launch_bounds__(256) void k_out(
    const unsigned short* __restrict__ bu16, const unsigned short* __restrict__ ubf,
    const float* __restrict__ X0_re, const float* __restrict__ X0_im,
    const float* __restrict__ lamre, const float* __restrict__ lamim,
    const unsigned short* __restrict__ W, float* __restrict__ y) {
  __shared__ unsigned short pre[CL][PRE_STRIDE];
  int blk = blockIdx.x;
  int b = blk >> 7, c = blk & (NC-1);
  int tid = threadIdx.x;
  int t0 = c*CL;
  // stage u tile (32x128 bf16) into pre[t][512+..]
  {
    const unsigned short* usrc = ubf + (size_t)(b*SEQ + t0)*HIN;
#pragma unroll
    for (int c2 = tid; c2 < 512; c2 += 256) {
      int t = c2 >> 4, h0 = (c2 & 15) * 8;
      *(short8*)&pre[t][2*NST + h0] = *(const short8*)&usrc[t*HIN + h0];
    }
  }
  // phase 1: preload ALL bu values into registers (64 independent loads in
  // flight -> one HBM latency), then serial local scan into pre (bf16).
  {
    int n = tid;
    int gg = n >> 6, nl = n & 63;
    int cre = gg*128 + nl, cim = cre + 64;     // permuted bu cols
    const unsigned short* bup = bu16 + (size_t)(b*SEQ + t0)*NBU;
    unsigned short rbr[CL], rbi[CL];
#pragma unroll
    for (int t = 0; t < CL; ++t) {
      rbr[t] = bup[(size_t)t*NBU + cre];
      rbi[t] = bup[(size_t)t*NBU + cim];
    }
    float lr = lamre[n], li = lamim[n];
    int idx = (b*NC + c)*NST + n;
    float xr = X0_re[idx], xi = X0_im[idx];
#pragma unroll
    for (int t = 0; t < CL; ++t) {
      pre[t][n]       = f2bf(xr);
      pre[t][NST + n] = f2bf(xi);
      float br = bf2f(rbr[t]);
      float bi = bf2f(rbi[t]);
      float nr = lr*xr - li*xi + br;
      float ni = lr*xi + li*xr + bi;
      xr = nr; xi = ni;
    }
  }
  __syncthreads();
  // phase 2: MFMA y[32 t][128 o] = pre[32][640] @ W[128][640]^T
  int wid = tid >> 6, lane = tid & 63;
  int lm = lane & 15, lq = lane >> 4;
  int tt = wid >> 1, oh = wid & 1;
  f32x4 acc[4];
#pragma unroll
  for (int j = 0; j < 4; ++j) acc[j] = (f32x4)0.f;
  for (int s = 0; s < 20; ++s) {
    int k0 = s*32 + lq*8;
    short8 a = *(const short8*)&pre[tt*16 + lm][k0];
#pragma unroll
    for (int j = 0; j < 4; ++j) {
      short8 bf = *(const short8*)&W[(size_t)(oh*64 + j*16 + lm)*KTOT + k0];
      acc[j] = __builtin_amdgcn_mfma_f32_16x16x32_bf16(a, bf, acc[j], 0, 0, 0);
    }
  }
#pragma unroll
  for (int j = 0; j < 4; ++j)
#pragma unroll
    for (int r = 0; r < 4; ++r)
      y[(size_t)(b*SEQ + t0 + tt*16 + lq*4 + r)*HOUT + oh*64 + j*16 + lm] = acc[j][r];
}

// --------------------------------------------------------------------------
extern "C" void kernel_launch(void* const* d_in, const int* in_sizes, int n_in,
                              void* d_out, int out_size, void* d_ws, size_t ws_size,
                              hipStream_t stream) {
  const float* u         = (const float*)d_in[0];
  const float* nu_log    = (const float*)d_in[1];
  const float* theta_log = (const float*)d_in[2];
  const float* gamma_log = (const float*)d_in[3];
  const float* B_re      = (const float*)d_in[4];
  const float* B_im      = (const float*)d_in[5];
  const float* C_re      = (const float*)d_in[6];
  const float* C_im      = (const float*)d_in[7];
  const float* Dm        = (const float*)d_in[8];
  float* y = (float*)d_out;
  char* ws = (char*)d_ws;

  float*          lamre = (float*)(ws);
  float*          lamim = (float*)(ws + 1024);
  unsigned short* ubf   = (unsigned short*)(ws + 4096);                       // 16 MB
  unsigned short* Wb    = (unsigned short*)(ws + 4096 + 16777216);            // 128 KB
  unsigned short* W     = (unsigned short*)(ws + 4096 + 16777216 + 131072);   // 160 KB
  unsigned short* bu16  = (unsigned short*)(ws + 4096 + 16777216 + 131072 + 163840); // 64 MB
  char* p2 = ws + 4096 + 16777216 + 131072 + 163840 + (size_t)ROWS*NBU*2;
  float* S_re  = (float*)(p2);
  float* S_im  = (float*)(p2 + 2097152);
  float* G_re  = (float*)(p2 + 2*2097152);
  float* G_im  = (float*)(p2 + 2*2097152 + 131072);
  float* X0_re = (float*)(p2 + 2*2097152 + 2*131072);
  float* X0_im = (float*)(p2 + 3*2097152 + 2*131072);

  k_prep<<<320, 256, 0, stream>>>(nu_log, theta_log, gamma_log, B_re, B_im,
                                  C_re, C_im, Dm, lamre, lamim, Wb, W);
  k_cast<<<(ROWS*HIN)/1024, 256, 0, stream>>>(u, ubf);
  k_bu<<<dim3(ROWS/128, 4), 256, 0, stream>>>(ubf, Wb, lamre, lamim,
                                              bu16, S_re, S_im);
  k_carry2<<<BATCH*8, 256, 0, stream>>>(S_re, S_im, lamre, lamim, G_re, G_im);
  k_final<<<BATCH*8, 256, 0, stream>>>(S_re, S_im, G_re, G_im, lamre, lamim,
                                       X0_re, X0_im);
  k_out<<<BATCH*NC, 256, 0, stream>>>(bu16, ubf, X0_re, X0_im, lamre, lamim, W, y);
}

// Round 6
// 189.359 us; speedup vs baseline: 2.8283x; 1.2588x over previous
//
#include <hip/hip_runtime.h>
#include <math.h>

// Problem constants
#define BATCH 16
#define SEQ   4096
#define HIN   128
#define NST   256
#define HOUT  128
#define CL    32              // chunk length for scan
#define NC    (SEQ/CL)        // 128 chunks
#define ROWS  (BATCH*SEQ)     // 65536
#define KTOT  640             // 256 re + 256 im + 128 u (output GEMM K)
#define NBU   512             // bu row width (permuted): g*128 + [re 64 | im 64]

typedef __attribute__((ext_vector_type(8))) short short8;
typedef __attribute__((ext_vector_type(4))) float f32x4;

__device__ inline unsigned short f2bf(float f) {
  union { float f; unsigned u; } v; v.f = f;
  unsigned r = v.u + 0x7FFFu + ((v.u >> 16) & 1u);   // RNE
  return (unsigned short)(r >> 16);
}
__device__ inline float bf2f(unsigned short s) {
  union { unsigned u; float f; } v; v.u = ((unsigned)s) << 16;
  return v.f;
}

// ------------------------------------------------------------- prep --------
// Wb rows PERMUTED: row r: g=r>>7, w=r&127; n = g*64 + (w&63);
//   w<64 -> gamma*B_re[n], else gamma*B_im[n].
// W = [C_re | -C_im | D] bf16 [128][640] (canonical n order).
__global__ __launch_bounds__(256) void k_prep(
    const float* __restrict__ nu_log, const float* __restrict__ theta_log,
    const float* __restrict__ gamma_log,
    const float* __restrict__ Bre, const float* __restrict__ Bim,
    const float* __restrict__ Cre, const float* __restrict__ Cim,
    const float* __restrict__ Dm,
    float* __restrict__ lamre, float* __restrict__ lamim,
    unsigned short* __restrict__ Wb, unsigned short* __restrict__ W) {
  int idx = blockIdx.x*256 + threadIdx.x;
  if (idx < NST) {
    float lm = expf(-expf(nu_log[idx]));
    float th = expf(theta_log[idx]);
    lamre[idx] = lm * cosf(th);
    lamim[idx] = lm * sinf(th);
  }
  if (idx < 512*HIN) {
    int r = idx >> 7, h = idx & 127;
    int g = r >> 7;
    int w = r & 127;
    int n = g*64 + (w & 63);
    float gm = expf(gamma_log[n]);
    float v = (w < 64) ? Bre[n*HIN + h] : Bim[n*HIN + h];
    Wb[idx] = f2bf(gm * v);
  }
  if (idx < HOUT*KTOT) {
    int o = idx / KTOT, k = idx - o*KTOT;
    float v;
    if (k < NST)        v =  Cre[o*NST + k];
    else if (k < 2*NST) v = -Cim[o*NST + (k - NST)];
    else                v =  Dm[o*HIN + (k - 2*NST)];
    W[idx] = f2bf(v);
  }
}

// ------------------------------------------------------- u -> bf16 cast ----
__global__ __launch_bounds__(256) void k_cast(
    const float* __restrict__ u, unsigned short* __restrict__ ubf) {
  size_t i = (size_t)(blockIdx.x*256 + threadIdx.x) * 4;
  float4 v = *(const float4*)(u + i);
  ushort4 o;
  o.x = f2bf(v.x); o.y = f2bf(v.y); o.z = f2bf(v.z); o.w = f2bf(v.w);
  *(ushort4*)(ubf + i) = o;
}

// ------------- bu GEMM (MFMA) + fused chunk-carry epilogue -----------------
// grid (ROWS/128, 4), block 256. Tile 128 t-rows x 128 cols (64 complex n).
// Stores bu bf16 (for k_scan local re-scan) and S_re/S_im f32 carries.
union SharedU {
  struct { unsigned short A[128][72], B[128][72]; } s1;   // 36.9 KB staging
  struct { float stg[2][32][132]; } s2;                   // 33.8 KB carry stage
};
__global__ __launch_bounds__(256) void k_bu(
    const unsigned short* __restrict__ ubf, const unsigned short* __restrict__ Wb,
    const float* __restrict__ lamre, const float* __restrict__ lamim,
    unsigned short* __restrict__ bu16,
    float* __restrict__ S_re, float* __restrict__ S_im) {
  __shared__ SharedU sh;
  int tid = threadIdx.x;
  int row0 = blockIdx.x * 128;
  int g    = blockIdx.y;
  int col0 = g * 128;
  int wid = tid >> 6, lane = tid & 63;
  int lm = lane & 15, lq = lane >> 4;
  int m0 = (wid >> 1) * 64, n0 = (wid & 1) * 64;
  f32x4 acc[4][4];
#pragma unroll
  for (int i = 0; i < 4; ++i)
#pragma unroll
    for (int j = 0; j < 4; ++j) acc[i][j] = (f32x4)0.f;
  for (int s = 0; s < 2; ++s) {
#pragma unroll
    for (int cc = 0; cc < 4; ++cc) {
      int ch = cc*256 + tid;               // 1024 chunks of 8 shorts
      int r = ch >> 3, h0 = (ch & 7) * 8;
      *(short8*)&sh.s1.A[r][h0] = *(const short8*)&ubf[(size_t)(row0 + r)*HIN + s*64 + h0];
      *(short8*)&sh.s1.B[r][h0] = *(const short8*)&Wb [(size_t)(col0 + r)*HIN + s*64 + h0];
    }
    __syncthreads();
#pragma unroll
    for (int ks = 0; ks < 2; ++ks) {
      int k0 = ks*32 + lq*8;
      short8 a[4], b[4];
#pragma unroll
      for (int i = 0; i < 4; ++i) a[i] = *(const short8*)&sh.s1.A[m0 + i*16 + lm][k0];
#pragma unroll
      for (int j = 0; j < 4; ++j) b[j] = *(const short8*)&sh.s1.B[n0 + j*16 + lm][k0];
#pragma unroll
      for (int i = 0; i < 4; ++i)
#pragma unroll
        for (int j = 0; j < 4; ++j)
          acc[i][j] = __builtin_amdgcn_mfma_f32_16x16x32_bf16(a[i], b[j], acc[i][j], 0, 0, 0);
    }
    __syncthreads();
  }
  // epilogue A: bf16 bu store (permuted col layout, matches Wb rows)
#pragma unroll
  for (int i = 0; i < 4; ++i)
#pragma unroll
    for (int j = 0; j < 4; ++j)
#pragma unroll
      for (int r = 0; r < 4; ++r)
        bu16[(size_t)(row0 + m0 + i*16 + lq*4 + r)*NBU + col0 + n0 + j*16 + lm] =
            f2bf(acc[i][j][r]);
  // epilogue B: f32 carries via LDS.
  int b = row0 >> 12;                 // SEQ = 4096
  int cbase = (row0 & 4095) >> 5;     // /CL
  for (int p = 0; p < 2; ++p) {
    __syncthreads();
#pragma unroll
    for (int ii = 0; ii < 2; ++ii) {
      int i = 2*p + ii;
#pragma unroll
      for (int j = 0; j < 4; ++j)
#pragma unroll
        for (int r = 0; r < 4; ++r) {
          int trow = ii*16 + lq*4 + r;              // 0..31 within chunk
          sh.s2.stg[wid >> 1][trow][n0 + j*16 + lm] = acc[i][j][r];
        }
    }
    __syncthreads();
    if (tid < 128) {
      int buf = tid >> 6, n = tid & 63;
      int ng = g*64 + n;
      float lr = lamre[ng], li = lamim[ng];
      float sr = 0.f, si = 0.f;
#pragma unroll
      for (int t = 0; t < 32; ++t) {
        float br = sh.s2.stg[buf][t][n];
        float bi = sh.s2.stg[buf][t][64 + n];
        float nr = lr*sr - li*si + br;
        float ni = lr*si + li*sr + bi;
        sr = nr; si = ni;
      }
      int c = cbase + p + 2*buf;
      int idx = (b*NC + c)*NST + ng;
      S_re[idx] = sr; S_im[idx] = si;
    }
  }
}

// ---------------- two-level scan of chunk carries -> X0 --------------------
// level 1: carries over groups of 16 chunks. grid BATCH*8, block 256.
__global__ __launch_bounds__(256) void k_carry2(
    const float* __restrict__ S_re, const float* __restrict__ S_im,
    const float* __restrict__ lamre, const float* __restrict__ lamim,
    float* __restrict__ G_re, float* __restrict__ G_im) {
  int blk = blockIdx.x;
  int b = blk >> 3, g = blk & 7;
  int n = threadIdx.x;
  float ar = lamre[n], ai = lamim[n];
#pragma unroll
  for (int s = 0; s < 5; ++s) { float nr = ar*ar - ai*ai, ni = 2.f*ar*ai; ar = nr; ai = ni; } // lam^32
  float tr = 0.f, ti = 0.f;
#pragma unroll
  for (int cc = 0; cc < 16; ++cc) {
    int idx = (b*NC + g*16 + cc)*NST + n;
    float nr = ar*tr - ai*ti + S_re[idx];
    float ni = ar*ti + ai*tr + S_im[idx];
    tr = nr; ti = ni;
  }
  int gi = (b*8 + g)*NST + n;
  G_re[gi] = tr; G_im[gi] = ti;
}

// level 2: group prefix then per-chunk X0. grid BATCH*8, block 256.
__global__ __launch_bounds__(256) void k_final(
    const float* __restrict__ S_re, const float* __restrict__ S_im,
    const float* __restrict__ G_re, const float* __restrict__ G_im,
    const float* __restrict__ lamre, const float* __restrict__ lamim,
    float* __restrict__ X0_re, float* __restrict__ X0_im) {
  int blk = blockIdx.x;
  int b = blk >> 3, g = blk & 7;
  int n = threadIdx.x;
  float ar = lamre[n], ai = lamim[n];
#pragma unroll
  for (int s = 0; s < 5; ++s) { float nr = ar*ar - ai*ai, ni = 2.f*ar*ai; ar = nr; ai = ni; } // lam^32
  float a5r = ar, a5i = ai;
#pragma unroll
  for (int s = 0; s < 4; ++s) { float nr = a5r*a5r - a5i*a5i, ni = 2.f*a5r*a5i; a5r = nr; a5i = ni; } // lam^512
  float pr = 0.f, pi = 0.f;
  for (int j = 0; j < g; ++j) {
    int gi = (b*8 + j)*NST + n;
    float nr = a5r*pr - a5i*pi + G_re[gi];
    float ni = a5r*pi + a5i*pr + G_im[gi];
    pr = nr; pi = ni;
  }
  float xr = pr, xi = pi;
#pragma unroll
  for (int cc = 0; cc < 16; ++cc) {
    int idx = (b*NC + g*16 + cc)*NST + n;
    X0_re[idx] = xr; X0_im[idx] = xi;
    float nr = ar*xr - ai*xi + S_re[idx];
    float ni = ar*xi + ai*xr + S_im[idx];
    xr = nr; xi = ni;
  }
}

// ---------------- local re-scan -> pre16 (A-matrix for output GEMM) --------
// grid BATCH*NC, block 256. Writes pre16[row][640] = [x_re 256 | x_im 256 | u 128].
__global__ __launch_bounds__(256) void k_scan(
    const unsigned short* __restrict__ bu16, const unsigned short* __restrict__ ubf,
    const float* __restrict__ X0_re, const float* __restrict__ X0_im,
    const float* __restrict__ lamre, const float* __restrict__ lamim,
    unsigned short* __restrict__ pre16) {
  int blk = blockIdx.x;
  int b = blk >> 7, c = blk & (NC-1);
  int tid = threadIdx.x;
  int t0 = c*CL;
  size_t rowbase = (size_t)(b*SEQ + t0);
  // u copy: cols 512..639 (32 rows x 128 shorts, short8 wide)
  {
    const unsigned short* usrc = ubf + rowbase*HIN;
    unsigned short* udst = pre16 + rowbase*KTOT + 2*NST;
#pragma unroll
    for (int c2 = tid; c2 < 512; c2 += 256) {
      int t = c2 >> 4, h0 = (c2 & 15) * 8;
      *(short8*)&udst[(size_t)t*KTOT + h0] = *(const short8*)&usrc[t*HIN + h0];
    }
  }
  // preload bu (64 independent loads in flight), then serial scan
  int n = tid;
  int gg = n >> 6, nl = n & 63;
  int cre = gg*128 + nl, cim = cre + 64;     // permuted bu cols
  const unsigned short* bup = bu16 + rowbase*NBU;
  unsigned short rbr[CL], rbi[CL];
#pragma unroll
  for (int t = 0; t < CL; ++t) {
    rbr[t] = bup[(size_t)t*NBU + cre];
    rbi[t] = bup[(size_t)t*NBU + cim];
  }
  float lr = lamre[n], li = lamim[n];
  int idx = (b*NC + c)*NST + n;
  float xr = X0_re[idx], xi = X0_im[idx];
  unsigned short* pdst = pre16 + rowbase*KTOT;
#pragma unroll
  for (int t = 0; t < CL; ++t) {
    pdst[n]       = f2bf(xr);
    pdst[NST + n] = f2bf(xi);
    float br = bf2f(rbr[t]);
    float bi = bf2f(rbi[t]);
    float nr = lr*xr - li*xi + br;
    float ni = lr*xi + li*xr + bi;
    xr = nr; xi = ni; pdst += KTOT;
  }
}

// ---------------- output GEMM: y = pre16 @ W^T  (MFMA, 128x128 tiles) ------
// grid ROWS/128 = 512, block 256. K=640 in 5 tiles of 128. LDS 69.6 KB -> 2/CU.
#define OP 8
__global__ __launch_bounds__(256) void k_out2(
    const unsigned short* __restrict__ pre16, const unsigned short* __restrict__ W,
    float* __restrict__ y) {
  __shared__ unsigned short Asl[128][128+OP];
  __shared__ unsigned short Bsl[128][128+OP];
  int tid = threadIdx.x;
  int row0 = blockIdx.x * 128;
  int wid = tid >> 6, lane = tid & 63;
  int lm = lane & 15, lq = lane >> 4;
  int m0 = (wid >> 1) * 64, n0 = (wid & 1) * 64;
  f32x4 acc[4][4];
#pragma unroll
  for (int i = 0; i < 4; ++i)
#pragma unroll
    for (int j = 0; j < 4; ++j) acc[i][j] = (f32x4)0.f;
  for (int s = 0; s < 5; ++s) {
#pragma unroll
    for (int cc = 0; cc < 8; ++cc) {
      int ch = cc*256 + tid;               // 2048 chunks of 8 shorts
      int r = ch >> 4, h0 = (ch & 15) * 8;
      *(short8*)&Asl[r][h0] = *(const short8*)&pre16[(size_t)(row0 + r)*KTOT + s*128 + h0];
      *(short8*)&Bsl[r][h0] = *(const short8*)&W[(size_t)r*KTOT + s*128 + h0];
    }
    __syncthreads();
#pragma unroll
    for (int ks = 0; ks < 4; ++ks) {
      int k0 = ks*32 + lq*8;
      short8 a[4], b[4];
#pragma unroll
      for (int i = 0; i < 4; ++i) a[i] = *(const short8*)&Asl[m0 + i*16 + lm][k0];
#pragma unroll
      for (int j = 0; j < 4; ++j) b[j] = *(const short8*)&Bsl[n0 + j*16 + lm][k0];
#pragma unroll
      for (int i = 0; i < 4; ++i)
#pragma unroll
        for (int j = 0; j < 4; ++j)
          acc[i][j] = __builtin_amdgcn_mfma_f32_16x16x32_bf16(a[i], b[j], acc[i][j], 0, 0, 0);
    }
    __syncthreads();
  }
#pragma unroll
  for (int i = 0; i < 4; ++i)
#pragma unroll
    for (int j = 0; j < 4; ++j)
#pragma unroll
      for (int r = 0; r < 4; ++r)
        y[(size_t)(row0 + m0 + i*16 + lq*4 + r)*HOUT + n0 + j*16 + lm] = acc[i][j][r];
}

// --------------------------------------------------------------------------
extern "C" void kernel_launch(void* const* d_in, const int* in_sizes, int n_in,
                              void* d_out, int out_size, void* d_ws, size_t ws_size,
                              hipStream_t stream) {
  const float* u         = (const float*)d_in[0];
  const float* nu_log    = (const float*)d_in[1];
  const float* theta_log = (const float*)d_in[2];
  const float* gamma_log = (const float*)d_in[3];
  const float* B_re      = (const float*)d_in[4];
  const float* B_im      = (const float*)d_in[5];
  const float* C_re      = (const float*)d_in[6];
  const float* C_im      = (const float*)d_in[7];
  const float* Dm        = (const float*)d_in[8];
  float* y = (float*)d_out;
  char* ws = (char*)d_ws;

  float*          lamre = (float*)(ws);
  float*          lamim = (float*)(ws + 1024);
  unsigned short* ubf   = (unsigned short*)(ws + 4096);                       // 16 MB
  unsigned short* Wb    = (unsigned short*)(ws + 4096 + 16777216);            // 128 KB
  unsigned short* W     = (unsigned short*)(ws + 4096 + 16777216 + 131072);   // 160 KB
  unsigned short* bu16  = (unsigned short*)(ws + 4096 + 16777216 + 131072 + 163840); // 64 MB
  char* pp = ws + 4096 + 16777216 + 131072 + 163840 + (size_t)ROWS*NBU*2;
  unsigned short* pre16 = (unsigned short*)pp;                                // 80 MB
  char* p2 = pp + (size_t)ROWS*KTOT*2;
  float* S_re  = (float*)(p2);
  float* S_im  = (float*)(p2 + 2097152);
  float* G_re  = (float*)(p2 + 2*2097152);
  float* G_im  = (float*)(p2 + 2*2097152 + 131072);
  float* X0_re = (float*)(p2 + 2*2097152 + 2*131072);
  float* X0_im = (float*)(p2 + 3*2097152 + 2*131072);

  k_prep<<<320, 256, 0, stream>>>(nu_log, theta_log, gamma_log, B_re, B_im,
                                  C_re, C_im, Dm, lamre, lamim, Wb, W);
  k_cast<<<(ROWS*HIN)/1024, 256, 0, stream>>>(u, ubf);
  k_bu<<<dim3(ROWS/128, 4), 256, 0, stream>>>(ubf, Wb, lamre, lamim,
                                              bu16, S_re, S_im);
  k_carry2<<<BATCH*8, 256, 0, stream>>>(S_re, S_im, lamre, lamim, G_re, G_im);
  k_final<<<BATCH*8, 256, 0, stream>>>(S_re, S_im, G_re, G_im, lamre, lamim,
                                       X0_re, X0_im);
  k_scan<<<BATCH*NC, 256, 0, stream>>>(bu16, ubf, X0_re, X0_im, lamre, lamim, pre16);
  k_out2<<<ROWS/128, 256, 0, stream>>>(pre16, W, y);
}

// Round 7
// 187.861 us; speedup vs baseline: 2.8509x; 1.0080x over previous
//
#include <hip/hip_runtime.h>
#include <math.h>

// Problem constants
#define BATCH 16
#define SEQ   4096
#define HIN   128
#define NST   256
#define HOUT  128
#define CL    32              // chunk length for scan
#define NC    (SEQ/CL)        // 128 chunks
#define ROWS  (BATCH*SEQ)     // 65536
#define KTOT  640             // W K layout: 256 re + 256 im + 128 u
#define NPRE  512             // pre16 row width: [x_re 256 | x_im 256]
#define NBU   512             // bu row width (permuted): g*128 + [re 64 | im 64]

typedef __attribute__((ext_vector_type(8))) short short8;
typedef __attribute__((ext_vector_type(4))) float f32x4;

__device__ inline unsigned short f2bf(float f) {
  union { float f; unsigned u; } v; v.f = f;
  unsigned r = v.u + 0x7FFFu + ((v.u >> 16) & 1u);   // RNE
  return (unsigned short)(r >> 16);
}
__device__ inline float bf2f(unsigned short s) {
  union { unsigned u; float f; } v; v.u = ((unsigned)s) << 16;
  return v.f;
}

// ------------------------------------------------------------- prep --------
// Wb rows PERMUTED: row r: g=r>>7, w=r&127; n = g*64 + (w&63);
//   w<64 -> gamma*B_re[n], else gamma*B_im[n].
// W = [C_re | -C_im | D] bf16 [128][640] (canonical order).
__global__ __launch_bounds__(256) void k_prep(
    const float* __restrict__ nu_log, const float* __restrict__ theta_log,
    const float* __restrict__ gamma_log,
    const float* __restrict__ Bre, const float* __restrict__ Bim,
    const float* __restrict__ Cre, const float* __restrict__ Cim,
    const float* __restrict__ Dm,
    float* __restrict__ lamre, float* __restrict__ lamim,
    unsigned short* __restrict__ Wb, unsigned short* __restrict__ W) {
  int idx = blockIdx.x*256 + threadIdx.x;
  if (idx < NST) {
    float lm = expf(-expf(nu_log[idx]));
    float th = expf(theta_log[idx]);
    lamre[idx] = lm * cosf(th);
    lamim[idx] = lm * sinf(th);
  }
  if (idx < 512*HIN) {
    int r = idx >> 7, h = idx & 127;
    int g = r >> 7;
    int w = r & 127;
    int n = g*64 + (w & 63);
    float gm = expf(gamma_log[n]);
    float v = (w < 64) ? Bre[n*HIN + h] : Bim[n*HIN + h];
    Wb[idx] = f2bf(gm * v);
  }
  if (idx < HOUT*KTOT) {
    int o = idx / KTOT, k = idx - o*KTOT;
    float v;
    if (k < NST)        v =  Cre[o*NST + k];
    else if (k < 2*NST) v = -Cim[o*NST + (k - NST)];
    else                v =  Dm[o*HIN + (k - 2*NST)];
    W[idx] = f2bf(v);
  }
}

// ------------------------------------------------------- u -> bf16 cast ----
__global__ __launch_bounds__(256) void k_cast(
    const float* __restrict__ u, unsigned short* __restrict__ ubf) {
  size_t i = (size_t)(blockIdx.x*256 + threadIdx.x) * 4;
  float4 v = *(const float4*)(u + i);
  ushort4 o;
  o.x = f2bf(v.x); o.y = f2bf(v.y); o.z = f2bf(v.z); o.w = f2bf(v.w);
  *(ushort4*)(ubf + i) = o;
}

// ------------- bu GEMM (MFMA) + fused chunk-carry epilogue -----------------
// grid ROWS/128 = 512 blocks. Block: 128 rows x 512 cols (4 col-groups).
// A (u-tile) staged ONCE; B restaged per group; carry stage overlays B (union).
union SharedBu {
  unsigned short B[128][136];   // 34.8 KB group staging
  float stg[2][32][132];        // 33.8 KB carry stage
};
__global__ __launch_bounds__(256) void k_bu(
    const unsigned short* __restrict__ ubf, const unsigned short* __restrict__ Wb,
    const float* __restrict__ lamre, const float* __restrict__ lamim,
    unsigned short* __restrict__ bu16,
    float* __restrict__ S_re, float* __restrict__ S_im) {
  __shared__ unsigned short Asl[128][136];   // 34.8 KB, resident whole kernel
  __shared__ SharedBu sh;
  int tid = threadIdx.x;
  int row0 = blockIdx.x * 128;
  int wid = tid >> 6, lane = tid & 63;
  int lm = lane & 15, lq = lane >> 4;
  int m0 = (wid >> 1) * 64, n0 = (wid & 1) * 64;
  int b = row0 >> 12;                 // / SEQ
  int cbase = (row0 & 4095) >> 5;     // / CL
  // stage A: 128 rows x 128 shorts
#pragma unroll
  for (int cc = 0; cc < 8; ++cc) {
    int ch = cc*256 + tid;
    int r = ch >> 4, h0 = (ch & 15) * 8;
    *(short8*)&Asl[r][h0] = *(const short8*)&ubf[(size_t)(row0 + r)*HIN + h0];
  }
  for (int g = 0; g < 4; ++g) {
    __syncthreads();    // A ready (g=0) / prior carry reads done (g>0)
#pragma unroll
    for (int cc = 0; cc < 8; ++cc) {
      int ch = cc*256 + tid;
      int r = ch >> 4, h0 = (ch & 15) * 8;
      *(short8*)&sh.B[r][h0] = *(const short8*)&Wb[(size_t)(g*128 + r)*HIN + h0];
    }
    __syncthreads();
    f32x4 acc[4][4];
#pragma unroll
    for (int i = 0; i < 4; ++i)
#pragma unroll
      for (int j = 0; j < 4; ++j) acc[i][j] = (f32x4)0.f;
#pragma unroll
    for (int ks = 0; ks < 4; ++ks) {
      int k0 = ks*32 + lq*8;
      short8 a[4], bb[4];
#pragma unroll
      for (int i = 0; i < 4; ++i) a[i] = *(const short8*)&Asl[m0 + i*16 + lm][k0];
#pragma unroll
      for (int j = 0; j < 4; ++j) bb[j] = *(const short8*)&sh.B[n0 + j*16 + lm][k0];
#pragma unroll
      for (int i = 0; i < 4; ++i)
#pragma unroll
        for (int j = 0; j < 4; ++j)
          acc[i][j] = __builtin_amdgcn_mfma_f32_16x16x32_bf16(a[i], bb[j], acc[i][j], 0, 0, 0);
    }
    // bu16 store (permuted col layout, matches Wb rows)
#pragma unroll
    for (int i = 0; i < 4; ++i)
#pragma unroll
      for (int j = 0; j < 4; ++j)
#pragma unroll
        for (int r = 0; r < 4; ++r)
          bu16[(size_t)(row0 + m0 + i*16 + lq*4 + r)*NBU + g*128 + n0 + j*16 + lm] =
              f2bf(acc[i][j][r]);
    // carry epilogue: chunks (buf = wave-half row block, p = chunk within)
    for (int p = 0; p < 2; ++p) {
      __syncthreads();   // B reads done (p=0) / prior scan reads done (p=1)
#pragma unroll
      for (int ii = 0; ii < 2; ++ii) {
        int i = 2*p + ii;
#pragma unroll
        for (int j = 0; j < 4; ++j)
#pragma unroll
          for (int r = 0; r < 4; ++r) {
            int trow = ii*16 + lq*4 + r;            // 0..31 within chunk
            sh.stg[wid >> 1][trow][n0 + j*16 + lm] = acc[i][j][r];
          }
      }
      __syncthreads();
      if (tid < 128) {
        int buf = tid >> 6, nl = tid & 63;
        int ng = g*64 + nl;
        float lr = lamre[ng], li = lamim[ng];
        float sr = 0.f, si = 0.f;
#pragma unroll
        for (int t = 0; t < 32; ++t) {
          float br = sh.stg[buf][t][nl];
          float bi = sh.stg[buf][t][64 + nl];
          float nr = lr*sr - li*si + br;
          float ni = lr*si + li*sr + bi;
          sr = nr; si = ni;
        }
        int c = cbase + buf*2 + p;
        int idx = (b*NC + c)*NST + ng;
        S_re[idx] = sr; S_im[idx] = si;
      }
    }
  }
}

// ---------------- two-level scan of chunk carries -> X0 --------------------
// level 1: carries over groups of 16 chunks. grid BATCH*8, block 256.
__global__ __launch_bounds__(256) void k_carry2(
    const float* __restrict__ S_re, const float* __restrict__ S_im,
    const float* __restrict__ lamre, const float* __restrict__ lamim,
    float* __restrict__ G_re, float* __restrict__ G_im) {
  int blk = blockIdx.x;
  int b = blk >> 3, g = blk & 7;
  int n = threadIdx.x;
  float ar = lamre[n], ai = lamim[n];
#pragma unroll
  for (int s = 0; s < 5; ++s) { float nr = ar*ar - ai*ai, ni = 2.f*ar*ai; ar = nr; ai = ni; } // lam^32
  float tr = 0.f, ti = 0.f;
#pragma unroll
  for (int cc = 0; cc < 16; ++cc) {
    int idx = (b*NC + g*16 + cc)*NST + n;
    float nr = ar*tr - ai*ti + S_re[idx];
    float ni = ar*ti + ai*tr + S_im[idx];
    tr = nr; ti = ni;
  }
  int gi = (b*8 + g)*NST + n;
  G_re[gi] = tr; G_im[gi] = ti;
}

// level 2: group prefix then per-chunk X0. grid BATCH*8, block 256.
__global__ __launch_bounds__(256) void k_final(
    const float* __restrict__ S_re, const float* __restrict__ S_im,
    const float* __restrict__ G_re, const float* __restrict__ G_im,
    const float* __restrict__ lamre, const float* __restrict__ lamim,
    float* __restrict__ X0_re, float* __restrict__ X0_im) {
  int blk = blockIdx.x;
  int b = blk >> 3, g = blk & 7;
  int n = threadIdx.x;
  float ar = lamre[n], ai = lamim[n];
#pragma unroll
  for (int s = 0; s < 5; ++s) { float nr = ar*ar - ai*ai, ni = 2.f*ar*ai; ar = nr; ai = ni; } // lam^32
  float a5r = ar, a5i = ai;
#pragma unroll
  for (int s = 0; s < 4; ++s) { float nr = a5r*a5r - a5i*a5i, ni = 2.f*a5r*a5i; a5r = nr; a5i = ni; } // lam^512
  float pr = 0.f, pi = 0.f;
  for (int j = 0; j < g; ++j) {
    int gi = (b*8 + j)*NST + n;
    float nr = a5r*pr - a5i*pi + G_re[gi];
    float ni = a5r*pi + a5i*pr + G_im[gi];
    pr = nr; pi = ni;
  }
  float xr = pr, xi = pi;
#pragma unroll
  for (int cc = 0; cc < 16; ++cc) {
    int idx = (b*NC + g*16 + cc)*NST + n;
    X0_re[idx] = xr; X0_im[idx] = xi;
    float nr = ar*xr - ai*xi + S_re[idx];
    float ni = ar*xi + ai*xr + S_im[idx];
    xr = nr; xi = ni;
  }
}

// ---------------- local re-scan -> pre16 [row][512] = [x_re | x_im] --------
// grid BATCH*NC, block 256.
__global__ __launch_bounds__(256) void k_scan(
    const unsigned short* __restrict__ bu16,
    const float* __restrict__ X0_re, const float* __restrict__ X0_im,
    const float* __restrict__ lamre, const float* __restrict__ lamim,
    unsigned short* __restrict__ pre16) {
  int blk = blockIdx.x;
  int b = blk >> 7, c = blk & (NC-1);
  int tid = threadIdx.x;
  int t0 = c*CL;
  size_t rowbase = (size_t)(b*SEQ + t0);
  int n = tid;
  int gg = n >> 6, nl = n & 63;
  int cre = gg*128 + nl, cim = cre + 64;     // permuted bu cols
  const unsigned short* bup = bu16 + rowbase*NBU;
  unsigned short rbr[CL], rbi[CL];
#pragma unroll
  for (int t = 0; t < CL; ++t) {
    rbr[t] = bup[(size_t)t*NBU + cre];
    rbi[t] = bup[(size_t)t*NBU + cim];
  }
  float lr = lamre[n], li = lamim[n];
  int idx = (b*NC + c)*NST + n;
  float xr = X0_re[idx], xi = X0_im[idx];
  unsigned short* pdst = pre16 + rowbase*NPRE;
#pragma unroll
  for (int t = 0; t < CL; ++t) {
    pdst[n]       = f2bf(xr);
    pdst[NST + n] = f2bf(xi);
    float br = bf2f(rbr[t]);
    float bi = bf2f(rbi[t]);
    float nr = lr*xr - li*xi + br;
    float ni = lr*xi + li*xr + bi;
    xr = nr; xi = ni; pdst += NPRE;
  }
}

// ---------------- output GEMM: y = [pre16 | ubf] @ W^T ---------------------
// grid ROWS/128 = 512, block 256. K=640: s=0..3 from pre16, s=4 from ubf.
__global__ __launch_bounds__(256) void k_out2(
    const unsigned short* __restrict__ pre16, const unsigned short* __restrict__ ubf,
    const unsigned short* __restrict__ W, float* __restrict__ y) {
  __shared__ unsigned short Asl[128][136];
  __shared__ unsigned short Bsl[128][136];
  int tid = threadIdx.x;
  int row0 = blockIdx.x * 128;
  int wid = tid >> 6, lane = tid & 63;
  int lm = lane & 15, lq = lane >> 4;
  int m0 = (wid >> 1) * 64, n0 = (wid & 1) * 64;
  f32x4 acc[4][4];
#pragma unroll
  for (int i = 0; i < 4; ++i)
#pragma unroll
    for (int j = 0; j < 4; ++j) acc[i][j] = (f32x4)0.f;
  for (int s = 0; s < 5; ++s) {
#pragma unroll
    for (int cc = 0; cc < 8; ++cc) {
      int ch = cc*256 + tid;
      int r = ch >> 4, h0 = (ch & 15) * 8;
      if (s < 4)
        *(short8*)&Asl[r][h0] = *(const short8*)&pre16[(size_t)(row0 + r)*NPRE + s*128 + h0];
      else
        *(short8*)&Asl[r][h0] = *(const short8*)&ubf[(size_t)(row0 + r)*HIN + h0];
      *(short8*)&Bsl[r][h0] = *(const short8*)&W[(size_t)r*KTOT + s*128 + h0];
    }
    __syncthreads();
#pragma unroll
    for (int ks = 0; ks < 4; ++ks) {
      int k0 = ks*32 + lq*8;
      short8 a[4], bb[4];
#pragma unroll
      for (int i = 0; i < 4; ++i) a[i] = *(const short8*)&Asl[m0 + i*16 + lm][k0];
#pragma unroll
      for (int j = 0; j < 4; ++j) bb[j] = *(const short8*)&Bsl[n0 + j*16 + lm][k0];
#pragma unroll
      for (int i = 0; i < 4; ++i)
#pragma unroll
        for (int j = 0; j < 4; ++j)
          acc[i][j] = __builtin_amdgcn_mfma_f32_16x16x32_bf16(a[i], bb[j], acc[i][j], 0, 0, 0);
    }
    __syncthreads();
  }
#pragma unroll
  for (int i = 0; i < 4; ++i)
#pragma unroll
    for (int j = 0; j < 4; ++j)
#pragma unroll
      for (int r = 0; r < 4; ++r)
        y[(size_t)(row0 + m0 + i*16 + lq*4 + r)*HOUT + n0 + j*16 + lm] = acc[i][j][r];
}

// --------------------------------------------------------------------------
extern "C" void kernel_launch(void* const* d_in, const int* in_sizes, int n_in,
                              void* d_out, int out_size, void* d_ws, size_t ws_size,
                              hipStream_t stream) {
  const float* u         = (const float*)d_in[0];
  const float* nu_log    = (const float*)d_in[1];
  const float* theta_log = (const float*)d_in[2];
  const float* gamma_log = (const float*)d_in[3];
  const float* B_re      = (const float*)d_in[4];
  const float* B_im      = (const float*)d_in[5];
  const float* C_re      = (const float*)d_in[6];
  const float* C_im      = (const float*)d_in[7];
  const float* Dm        = (const float*)d_in[8];
  float* y = (float*)d_out;
  char* ws = (char*)d_ws;

  float*          lamre = (float*)(ws);
  float*          lamim = (float*)(ws + 1024);
  unsigned short* ubf   = (unsigned short*)(ws + 4096);                       // 16 MB
  unsigned short* Wb    = (unsigned short*)(ws + 4096 + 16777216);            // 128 KB
  unsigned short* W     = (unsigned short*)(ws + 4096 + 16777216 + 131072);   // 160 KB
  unsigned short* bu16  = (unsigned short*)(ws + 4096 + 16777216 + 131072 + 163840); // 64 MB
  char* pp = ws + 4096 + 16777216 + 131072 + 163840 + (size_t)ROWS*NBU*2;
  unsigned short* pre16 = (unsigned short*)pp;                                // 64 MB
  char* p2 = pp + (size_t)ROWS*NPRE*2;
  float* S_re  = (float*)(p2);
  float* S_im  = (float*)(p2 + 2097152);
  float* G_re  = (float*)(p2 + 2*2097152);
  float* G_im  = (float*)(p2 + 2*2097152 + 131072);
  float* X0_re = (float*)(p2 + 2*2097152 + 2*131072);
  float* X0_im = (float*)(p2 + 3*2097152 + 2*131072);

  k_prep<<<320, 256, 0, stream>>>(nu_log, theta_log, gamma_log, B_re, B_im,
                                  C_re, C_im, Dm, lamre, lamim, Wb, W);
  k_cast<<<(ROWS*HIN)/1024, 256, 0, stream>>>(u, ubf);
  k_bu<<<ROWS/128, 256, 0, stream>>>(ubf, Wb, lamre, lamim, bu16, S_re, S_im);
  k_carry2<<<BATCH*8, 256, 0, stream>>>(S_re, S_im, lamre, lamim, G_re, G_im);
  k_final<<<BATCH*8, 256, 0, stream>>>(S_re, S_im, G_re, G_im, lamre, lamim,
                                       X0_re, X0_im);
  k_scan<<<BATCH*NC, 256, 0, stream>>>(bu16, X0_re, X0_im, lamre, lamim, pre16);
  k_out2<<<ROWS/128, 256, 0, stream>>>(pre16, ubf, W, y);
}

// Round 8
// 181.022 us; speedup vs baseline: 2.9586x; 1.0378x over previous
//
#include <hip/hip_runtime.h>
#include <math.h>

// Problem constants
#define BATCH 16
#define SEQ   4096
#define HIN   128
#define NST   256
#define HOUT  128
#define CL    32              // chunk length for scan
#define NC    (SEQ/CL)        // 128 chunks
#define ROWS  (BATCH*SEQ)     // 65536
#define KTOT  640             // W K layout: 256 re + 256 im + 128 u
#define NPRE  512             // preL row width: [x_re 256 | x_im 256]

typedef __attribute__((ext_vector_type(8))) short short8;
typedef __attribute__((ext_vector_type(4))) float f32x4;

__device__ inline unsigned short f2bf(float f) {
  union { float f; unsigned u; } v; v.f = f;
  unsigned r = v.u + 0x7FFFu + ((v.u >> 16) & 1u);   // RNE
  return (unsigned short)(r >> 16);
}
__device__ inline float bf2f(unsigned short s) {
  union { unsigned u; float f; } v; v.u = ((unsigned)s) << 16;
  return v.f;
}

// ------------------------------------------------------------- prep --------
// Wb rows PERMUTED: row r: g=r>>7, w=r&127; n = g*64 + (w&63);
//   w<64 -> gamma*B_re[n], else gamma*B_im[n].
// W = [C_re | -C_im | D] bf16 [128][640].
// lamPow[j][n] = lambda_n^j, j=0..31 (f32), for the scan fix-up in k_out2.
__global__ __launch_bounds__(256) void k_prep(
    const float* __restrict__ nu_log, const float* __restrict__ theta_log,
    const float* __restrict__ gamma_log,
    const float* __restrict__ Bre, const float* __restrict__ Bim,
    const float* __restrict__ Cre, const float* __restrict__ Cim,
    const float* __restrict__ Dm,
    float* __restrict__ lamre, float* __restrict__ lamim,
    float* __restrict__ lamPowRe, float* __restrict__ lamPowIm,
    unsigned short* __restrict__ Wb, unsigned short* __restrict__ W) {
  int idx = blockIdx.x*256 + threadIdx.x;
  if (idx < NST) {
    float lm = expf(-expf(nu_log[idx]));
    float th = expf(theta_log[idx]);
    float lr = lm * cosf(th), li = lm * sinf(th);
    lamre[idx] = lr; lamim[idx] = li;
    float pr = 1.f, pi = 0.f;
    for (int j = 0; j < CL; ++j) {
      lamPowRe[j*NST + idx] = pr;
      lamPowIm[j*NST + idx] = pi;
      float nr = pr*lr - pi*li;
      float ni = pr*li + pi*lr;
      pr = nr; pi = ni;
    }
  }
  if (idx < 512*HIN) {
    int r = idx >> 7, h = idx & 127;
    int g = r >> 7;
    int w = r & 127;
    int n = g*64 + (w & 63);
    float gm = expf(gamma_log[n]);
    float v = (w < 64) ? Bre[n*HIN + h] : Bim[n*HIN + h];
    Wb[idx] = f2bf(gm * v);
  }
  if (idx < HOUT*KTOT) {
    int o = idx / KTOT, k = idx - o*KTOT;
    float v;
    if (k < NST)        v =  Cre[o*NST + k];
    else if (k < 2*NST) v = -Cim[o*NST + (k - NST)];
    else                v =  Dm[o*HIN + (k - 2*NST)];
    W[idx] = f2bf(v);
  }
}

// ------------------------------------------------------- u -> bf16 cast ----
__global__ __launch_bounds__(256) void k_cast(
    const float* __restrict__ u, unsigned short* __restrict__ ubf) {
  size_t i = (size_t)(blockIdx.x*256 + threadIdx.x) * 4;
  float4 v = *(const float4*)(u + i);
  ushort4 o;
  o.x = f2bf(v.x); o.y = f2bf(v.y); o.z = f2bf(v.z); o.w = f2bf(v.w);
  *(ushort4*)(ubf + i) = o;
}

// -------- bu GEMM (MFMA) + fused local-prefix + chunk-carry epilogue -------
// grid ROWS/128 = 512. Block: 128 rows x 512 cols (4 col-groups).
// Emits preL (bf16 zero-init local prefix states, canonical n order) and
// S_re/S_im (f32 chunk carries). bu itself is never materialized.
union SharedBu {
  unsigned short B[128][136];   // 34.8 KB group staging
  float stg[2][32][132];        // 33.8 KB carry stage
};
__global__ __launch_bounds__(256) void k_bu(
    const unsigned short* __restrict__ ubf, const unsigned short* __restrict__ Wb,
    const float* __restrict__ lamre, const float* __restrict__ lamim,
    unsigned short* __restrict__ preL,
    float* __restrict__ S_re, float* __restrict__ S_im) {
  __shared__ unsigned short Asl[128][136];   // resident whole kernel
  __shared__ SharedBu sh;
  int tid = threadIdx.x;
  int row0 = blockIdx.x * 128;
  int wid = tid >> 6, lane = tid & 63;
  int lm = lane & 15, lq = lane >> 4;
  int m0 = (wid >> 1) * 64, n0 = (wid & 1) * 64;
  int b = row0 >> 12;                 // / SEQ
  int cbase = (row0 & 4095) >> 5;     // / CL
  // stage A: 128 rows x 128 shorts
#pragma unroll
  for (int cc = 0; cc < 8; ++cc) {
    int ch = cc*256 + tid;
    int r = ch >> 4, h0 = (ch & 15) * 8;
    *(short8*)&Asl[r][h0] = *(const short8*)&ubf[(size_t)(row0 + r)*HIN + h0];
  }
  for (int g = 0; g < 4; ++g) {
    __syncthreads();    // A ready (g=0) / prior carry reads done (g>0)
#pragma unroll
    for (int cc = 0; cc < 8; ++cc) {
      int ch = cc*256 + tid;
      int r = ch >> 4, h0 = (ch & 15) * 8;
      *(short8*)&sh.B[r][h0] = *(const short8*)&Wb[(size_t)(g*128 + r)*HIN + h0];
    }
    __syncthreads();
    f32x4 acc[4][4];
#pragma unroll
    for (int i = 0; i < 4; ++i)
#pragma unroll
      for (int j = 0; j < 4; ++j) acc[i][j] = (f32x4)0.f;
#pragma unroll
    for (int ks = 0; ks < 4; ++ks) {
      int k0 = ks*32 + lq*8;
      short8 a[4], bb[4];
#pragma unroll
      for (int i = 0; i < 4; ++i) a[i] = *(const short8*)&Asl[m0 + i*16 + lm][k0];
#pragma unroll
      for (int j = 0; j < 4; ++j) bb[j] = *(const short8*)&sh.B[n0 + j*16 + lm][k0];
#pragma unroll
      for (int i = 0; i < 4; ++i)
#pragma unroll
        for (int j = 0; j < 4; ++j)
          acc[i][j] = __builtin_amdgcn_mfma_f32_16x16x32_bf16(a[i], bb[j], acc[i][j], 0, 0, 0);
    }
    // epilogue: per chunk-pair, stage acc to LDS, serial scan emitting
    // local prefix states (bf16) + final carry (f32).
    for (int p = 0; p < 2; ++p) {
      __syncthreads();   // B reads done (p=0) / prior scan reads done (p=1)
#pragma unroll
      for (int ii = 0; ii < 2; ++ii) {
        int i = 2*p + ii;
#pragma unroll
        for (int j = 0; j < 4; ++j)
#pragma unroll
          for (int r = 0; r < 4; ++r) {
            int trow = ii*16 + lq*4 + r;            // 0..31 within chunk
            sh.stg[wid >> 1][trow][n0 + j*16 + lm] = acc[i][j][r];
          }
      }
      __syncthreads();
      if (tid < 128) {
        int buf = tid >> 6, nl = tid & 63;
        int ng = g*64 + nl;
        float lr = lamre[ng], li = lamim[ng];
        float rr[CL], ri[CL];
#pragma unroll
        for (int t = 0; t < CL; ++t) {
          rr[t] = sh.stg[buf][t][nl];
          ri[t] = sh.stg[buf][t][64 + nl];
        }
        int rowb = row0 + buf*64 + p*32;
        unsigned short* pl = preL + (size_t)rowb*NPRE;
        float sr = 0.f, si = 0.f;
#pragma unroll
        for (int t = 0; t < CL; ++t) {
          pl[ng]       = f2bf(sr);     // local prefix BEFORE step t
          pl[NST + ng] = f2bf(si);
          float nr = lr*sr - li*si + rr[t];
          float ni = lr*si + li*sr + ri[t];
          sr = nr; si = ni; pl += NPRE;
        }
        int c = cbase + buf*2 + p;
        int idx = (b*NC + c)*NST + ng;
        S_re[idx] = sr; S_im[idx] = si;
      }
    }
  }
}

// ---------------- two-level scan of chunk carries -> X0 --------------------
// level 1: carries over groups of 16 chunks. grid BATCH*8, block 256.
__global__ __launch_bounds__(256) void k_carry2(
    const float* __restrict__ S_re, const float* __restrict__ S_im,
    const float* __restrict__ lamre, const float* __restrict__ lamim,
    float* __restrict__ G_re, float* __restrict__ G_im) {
  int blk = blockIdx.x;
  int b = blk >> 3, g = blk & 7;
  int n = threadIdx.x;
  float ar = lamre[n], ai = lamim[n];
#pragma unroll
  for (int s = 0; s < 5; ++s) { float nr = ar*ar - ai*ai, ni = 2.f*ar*ai; ar = nr; ai = ni; } // lam^32
  float tr = 0.f, ti = 0.f;
#pragma unroll
  for (int cc = 0; cc < 16; ++cc) {
    int idx = (b*NC + g*16 + cc)*NST + n;
    float nr = ar*tr - ai*ti + S_re[idx];
    float ni = ar*ti + ai*tr + S_im[idx];
    tr = nr; ti = ni;
  }
  int gi = (b*8 + g)*NST + n;
  G_re[gi] = tr; G_im[gi] = ti;
}

// level 2: group prefix then per-chunk X0. grid BATCH*8, block 256.
__global__ __launch_bounds__(256) void k_final(
    const float* __restrict__ S_re, const float* __restrict__ S_im,
    const float* __restrict__ G_re, const float* __restrict__ G_im,
    const float* __restrict__ lamre, const float* __restrict__ lamim,
    float* __restrict__ X0_re, float* __restrict__ X0_im) {
  int blk = blockIdx.x;
  int b = blk >> 3, g = blk & 7;
  int n = threadIdx.x;
  float ar = lamre[n], ai = lamim[n];
#pragma unroll
  for (int s = 0; s < 5; ++s) { float nr = ar*ar - ai*ai, ni = 2.f*ar*ai; ar = nr; ai = ni; } // lam^32
  float a5r = ar, a5i = ai;
#pragma unroll
  for (int s = 0; s < 4; ++s) { float nr = a5r*a5r - a5i*a5i, ni = 2.f*a5r*a5i; a5r = nr; a5i = ni; } // lam^512
  float pr = 0.f, pi = 0.f;
  for (int j = 0; j < g; ++j) {
    int gi = (b*8 + j)*NST + n;
    float nr = a5r*pr - a5i*pi + G_re[gi];
    float ni = a5r*pi + a5i*pr + G_im[gi];
    pr = nr; pi = ni;
  }
  float xr = pr, xi = pi;
#pragma unroll
  for (int cc = 0; cc < 16; ++cc) {
    int idx = (b*NC + g*16 + cc)*NST + n;
    X0_re[idx] = xr; X0_im[idx] = xi;
    float nr = ar*xr - ai*xi + S_re[idx];
    float ni = ar*xi + ai*xr + S_im[idx];
    xr = nr; xi = ni;
  }
}

// ------- output GEMM with fused scan fix-up in A-staging -------------------
// y[128 rows][128 o] = [fix(preL) | ubf] @ W^T.
// fix: pre[row][n] = preL[row][n] + lam^j * X0[chunk(row)][n], j = row & 31.
// grid ROWS/128 = 512, block 256. K=640: s=0..3 from preL(+fix), s=4 from ubf.
__global__ __launch_bounds__(256) void k_out2(
    const unsigned short* __restrict__ preL, const unsigned short* __restrict__ ubf,
    const unsigned short* __restrict__ W,
    const float* __restrict__ lamPowRe, const float* __restrict__ lamPowIm,
    const float* __restrict__ X0_re, const float* __restrict__ X0_im,
    float* __restrict__ y) {
  __shared__ unsigned short Asl[128][136];
  __shared__ unsigned short Bsl[128][136];
  int tid = threadIdx.x;
  int row0 = blockIdx.x * 128;
  int wid = tid >> 6, lane = tid & 63;
  int lm = lane & 15, lq = lane >> 4;
  int m0 = (wid >> 1) * 64, n0 = (wid & 1) * 64;
  f32x4 acc[4][4];
#pragma unroll
  for (int i = 0; i < 4; ++i)
#pragma unroll
    for (int j = 0; j < 4; ++j) acc[i][j] = (f32x4)0.f;
  for (int s = 0; s < 5; ++s) {
#pragma unroll
    for (int cc = 0; cc < 8; ++cc) {
      int ch = cc*256 + tid;
      int r = ch >> 4, h0 = (ch & 15) * 8;
      if (s < 4) {
        int row = row0 + r;
        int j = row & 31, cidx = row >> 5;
        int n = ((s & 1) << 7) + h0;
        short8 loc = *(const short8*)&preL[(size_t)row*NPRE + s*128 + h0];
        float lre[8], lim_[8], x0r[8], x0i[8];
        *(float4*)&lre[0]  = *(const float4*)&lamPowRe[j*NST + n];
        *(float4*)&lre[4]  = *(const float4*)&lamPowRe[j*NST + n + 4];
        *(float4*)&lim_[0] = *(const float4*)&lamPowIm[j*NST + n];
        *(float4*)&lim_[4] = *(const float4*)&lamPowIm[j*NST + n + 4];
        *(float4*)&x0r[0]  = *(const float4*)&X0_re[cidx*NST + n];
        *(float4*)&x0r[4]  = *(const float4*)&X0_re[cidx*NST + n + 4];
        *(float4*)&x0i[0]  = *(const float4*)&X0_im[cidx*NST + n];
        *(float4*)&x0i[4]  = *(const float4*)&X0_im[cidx*NST + n + 4];
        unsigned short o[8];
#pragma unroll
        for (int e = 0; e < 8; ++e) {
          float lv = bf2f((unsigned short)loc[e]);
          float v = (s < 2) ? (lv + lre[e]*x0r[e] - lim_[e]*x0i[e])
                            : (lv + lre[e]*x0i[e] + lim_[e]*x0r[e]);
          o[e] = f2bf(v);
        }
        *(short8*)&Asl[r][h0] = *(const short8*)o;
      } else {
        *(short8*)&Asl[r][h0] = *(const short8*)&ubf[(size_t)(row0 + r)*HIN + h0];
      }
      *(short8*)&Bsl[r][h0] = *(const short8*)&W[(size_t)r*KTOT + s*128 + h0];
    }
    __syncthreads();
#pragma unroll
    for (int ks = 0; ks < 4; ++ks) {
      int k0 = ks*32 + lq*8;
      short8 a[4], bb[4];
#pragma unroll
      for (int i = 0; i < 4; ++i) a[i] = *(const short8*)&Asl[m0 + i*16 + lm][k0];
#pragma unroll
      for (int j = 0; j < 4; ++j) bb[j] = *(const short8*)&Bsl[n0 + j*16 + lm][k0];
#pragma unroll
      for (int i = 0; i < 4; ++i)
#pragma unroll
        for (int j = 0; j < 4; ++j)
          acc[i][j] = __builtin_amdgcn_mfma_f32_16x16x32_bf16(a[i], bb[j], acc[i][j], 0, 0, 0);
    }
    __syncthreads();
  }
#pragma unroll
  for (int i = 0; i < 4; ++i)
#pragma unroll
    for (int j = 0; j < 4; ++j)
#pragma unroll
      for (int r = 0; r < 4; ++r)
        y[(size_t)(row0 + m0 + i*16 + lq*4 + r)*HOUT + n0 + j*16 + lm] = acc[i][j][r];
}

// --------------------------------------------------------------------------
extern "C" void kernel_launch(void* const* d_in, const int* in_sizes, int n_in,
                              void* d_out, int out_size, void* d_ws, size_t ws_size,
                              hipStream_t stream) {
  const float* u         = (const float*)d_in[0];
  const float* nu_log    = (const float*)d_in[1];
  const float* theta_log = (const float*)d_in[2];
  const float* gamma_log = (const float*)d_in[3];
  const float* B_re      = (const float*)d_in[4];
  const float* B_im      = (const float*)d_in[5];
  const float* C_re      = (const float*)d_in[6];
  const float* C_im      = (const float*)d_in[7];
  const float* Dm        = (const float*)d_in[8];
  float* y = (float*)d_out;
  char* ws = (char*)d_ws;

  float*          lamre    = (float*)(ws);
  float*          lamim    = (float*)(ws + 1024);
  float*          lamPowRe = (float*)(ws + 4096);            // 32 KB
  float*          lamPowIm = (float*)(ws + 4096 + 32768);    // 32 KB
  unsigned short* ubf      = (unsigned short*)(ws + 69632);                 // 16 MB
  unsigned short* Wb       = (unsigned short*)(ws + 69632 + 16777216);      // 128 KB
  unsigned short* W        = (unsigned short*)(ws + 69632 + 16777216 + 131072); // 160 KB
  unsigned short* preL     = (unsigned short*)(ws + 69632 + 16777216 + 131072 + 163840); // 64 MB
  char* p2 = ws + 69632 + 16777216 + 131072 + 163840 + (size_t)ROWS*NPRE*2;
  float* S_re  = (float*)(p2);
  float* S_im  = (float*)(p2 + 2097152);
  float* G_re  = (float*)(p2 + 2*2097152);
  float* G_im  = (float*)(p2 + 2*2097152 + 131072);
  float* X0_re = (float*)(p2 + 2*2097152 + 2*131072);
  float* X0_im = (float*)(p2 + 3*2097152 + 2*131072);

  k_prep<<<320, 256, 0, stream>>>(nu_log, theta_log, gamma_log, B_re, B_im,
                                  C_re, C_im, Dm, lamre, lamim,
                                  lamPowRe, lamPowIm, Wb, W);
  k_cast<<<(ROWS*HIN)/1024, 256, 0, stream>>>(u, ubf);
  k_bu<<<ROWS/128, 256, 0, stream>>>(ubf, Wb, lamre, lamim, preL, S_re, S_im);
  k_carry2<<<BATCH*8, 256, 0, stream>>>(S_re, S_im, lamre, lamim, G_re, G_im);
  k_final<<<BATCH*8, 256, 0, stream>>>(S_re, S_im, G_re, G_im, lamre, lamim,
                                       X0_re, X0_im);
  k_out2<<<ROWS/128, 256, 0, stream>>>(preL, ubf, W, lamPowRe, lamPowIm,
                                       X0_re, X0_im, y);
}

// Round 9
// 172.286 us; speedup vs baseline: 3.1086x; 1.0507x over previous
//
#include <hip/hip_runtime.h>
#include <math.h>

// Problem constants
#define BATCH 16
#define SEQ   4096
#define HIN   128
#define NST   256
#define HOUT  128
#define CL    32              // chunk length for scan
#define NC    (SEQ/CL)        // 128 chunks
#define ROWS  (BATCH*SEQ)     // 65536
#define KTOT  640             // W K layout: 256 re + 256 im + 128 u
#define NPRE  512             // preL row width: [x_re 256 | x_im 256]

typedef __attribute__((ext_vector_type(8))) short short8;
typedef __attribute__((ext_vector_type(4))) float f32x4;

__device__ inline unsigned short f2bf(float f) {
  union { float f; unsigned u; } v; v.f = f;
  unsigned r = v.u + 0x7FFFu + ((v.u >> 16) & 1u);   // RNE
  return (unsigned short)(r >> 16);
}
__device__ inline float bf2f(unsigned short s) {
  union { unsigned u; float f; } v; v.u = ((unsigned)s) << 16;
  return v.f;
}
__device__ inline float bits2f(unsigned u) {
  union { unsigned u; float f; } v; v.u = u; return v.f;
}

// ------------------------------------------------------------- prep --------
// Wb rows PERMUTED: row r: g=r>>7, w=r&127; n = g*64 + (w&63);
//   w<64 -> gamma*B_re[n], else gamma*B_im[n].
// W = [C_re | -C_im | D] bf16 [128][640].
// lamPk[j][n] = packed bf16 (re lo, im hi) of lambda_n^j, j=0..31.
__global__ __launch_bounds__(256) void k_prep(
    const float* __restrict__ nu_log, const float* __restrict__ theta_log,
    const float* __restrict__ gamma_log,
    const float* __restrict__ Bre, const float* __restrict__ Bim,
    const float* __restrict__ Cre, const float* __restrict__ Cim,
    const float* __restrict__ Dm,
    float* __restrict__ lamre, float* __restrict__ lamim,
    unsigned* __restrict__ lamPk,
    unsigned short* __restrict__ Wb, unsigned short* __restrict__ W) {
  int idx = blockIdx.x*256 + threadIdx.x;
  if (idx < NST) {
    float lm = expf(-expf(nu_log[idx]));
    float th = expf(theta_log[idx]);
    float lr = lm * cosf(th), li = lm * sinf(th);
    lamre[idx] = lr; lamim[idx] = li;
    float pr = 1.f, pi = 0.f;
    for (int j = 0; j < CL; ++j) {
      lamPk[j*NST + idx] = ((unsigned)f2bf(pi) << 16) | (unsigned)f2bf(pr);
      float nr = pr*lr - pi*li;
      float ni = pr*li + pi*lr;
      pr = nr; pi = ni;
    }
  }
  if (idx < 512*HIN) {
    int r = idx >> 7, h = idx & 127;
    int g = r >> 7;
    int w = r & 127;
    int n = g*64 + (w & 63);
    float gm = expf(gamma_log[n]);
    float v = (w < 64) ? Bre[n*HIN + h] : Bim[n*HIN + h];
    Wb[idx] = f2bf(gm * v);
  }
  if (idx < HOUT*KTOT) {
    int o = idx / KTOT, k = idx - o*KTOT;
    float v;
    if (k < NST)        v =  Cre[o*NST + k];
    else if (k < 2*NST) v = -Cim[o*NST + (k - NST)];
    else                v =  Dm[o*HIN + (k - 2*NST)];
    W[idx] = f2bf(v);
  }
}

// -------- bu GEMM (MFMA) + fused local-prefix + chunk-carry epilogue -------
// grid ROWS/128 = 512. Block: 128 rows x 512 cols (4 col-groups).
// Reads u f32 directly (converts during staging). Emits preL (bf16 local
// prefix states) + S_re/S_im (f32 chunk carries). bu never materialized.
union SharedBu {
  unsigned short B[128][136];   // 34.8 KB group staging
  float stg[2][32][132];        // 33.8 KB carry stage
};
__global__ __launch_bounds__(256) void k_bu(
    const float* __restrict__ u, const unsigned short* __restrict__ Wb,
    const float* __restrict__ lamre, const float* __restrict__ lamim,
    unsigned short* __restrict__ preL,
    float* __restrict__ S_re, float* __restrict__ S_im) {
  __shared__ unsigned short Asl[128][136];   // resident whole kernel
  __shared__ SharedBu sh;
  int tid = threadIdx.x;
  int row0 = blockIdx.x * 128;
  int wid = tid >> 6, lane = tid & 63;
  int lm = lane & 15, lq = lane >> 4;
  int m0 = (wid >> 1) * 64, n0 = (wid & 1) * 64;
  int b = row0 >> 12;                 // / SEQ
  int cbase = (row0 & 4095) >> 5;     // / CL
  // stage A: 128 rows x 128 f32 -> bf16
#pragma unroll
  for (int cc = 0; cc < 8; ++cc) {
    int ch = cc*256 + tid;
    int r = ch >> 4, h0 = (ch & 15) * 8;
    const float* src = u + (size_t)(row0 + r)*HIN + h0;
    float4 v0 = *(const float4*)src;
    float4 v1 = *(const float4*)(src + 4);
    unsigned short o[8];
    o[0]=f2bf(v0.x); o[1]=f2bf(v0.y); o[2]=f2bf(v0.z); o[3]=f2bf(v0.w);
    o[4]=f2bf(v1.x); o[5]=f2bf(v1.y); o[6]=f2bf(v1.z); o[7]=f2bf(v1.w);
    *(short8*)&Asl[r][h0] = *(const short8*)o;
  }
  for (int g = 0; g < 4; ++g) {
    __syncthreads();    // A ready (g=0) / prior carry reads done (g>0)
#pragma unroll
    for (int cc = 0; cc < 8; ++cc) {
      int ch = cc*256 + tid;
      int r = ch >> 4, h0 = (ch & 15) * 8;
      *(short8*)&sh.B[r][h0] = *(const short8*)&Wb[(size_t)(g*128 + r)*HIN + h0];
    }
    __syncthreads();
    f32x4 acc[4][4];
#pragma unroll
    for (int i = 0; i < 4; ++i)
#pragma unroll
      for (int j = 0; j < 4; ++j) acc[i][j] = (f32x4)0.f;
#pragma unroll
    for (int ks = 0; ks < 4; ++ks) {
      int k0 = ks*32 + lq*8;
      short8 a[4], bb[4];
#pragma unroll
      for (int i = 0; i < 4; ++i) a[i] = *(const short8*)&Asl[m0 + i*16 + lm][k0];
#pragma unroll
      for (int j = 0; j < 4; ++j) bb[j] = *(const short8*)&sh.B[n0 + j*16 + lm][k0];
#pragma unroll
      for (int i = 0; i < 4; ++i)
#pragma unroll
        for (int j = 0; j < 4; ++j)
          acc[i][j] = __builtin_amdgcn_mfma_f32_16x16x32_bf16(a[i], bb[j], acc[i][j], 0, 0, 0);
    }
    // epilogue: per chunk-pair, stage acc to LDS, serial scan emitting
    // local prefix states (bf16) + final carry (f32).
    for (int p = 0; p < 2; ++p) {
      __syncthreads();   // B reads done (p=0) / prior scan reads done (p=1)
#pragma unroll
      for (int ii = 0; ii < 2; ++ii) {
        int i = 2*p + ii;
#pragma unroll
        for (int j = 0; j < 4; ++j)
#pragma unroll
          for (int r = 0; r < 4; ++r) {
            int trow = ii*16 + lq*4 + r;            // 0..31 within chunk
            sh.stg[wid >> 1][trow][n0 + j*16 + lm] = acc[i][j][r];
          }
      }
      __syncthreads();
      if (tid < 128) {
        int buf = tid >> 6, nl = tid & 63;
        int ng = g*64 + nl;
        float lr = lamre[ng], li = lamim[ng];
        float rr[CL], ri[CL];
#pragma unroll
        for (int t = 0; t < CL; ++t) {
          rr[t] = sh.stg[buf][t][nl];
          ri[t] = sh.stg[buf][t][64 + nl];
        }
        int rowb = row0 + buf*64 + p*32;
        unsigned short* pl = preL + (size_t)rowb*NPRE;
        float sr = 0.f, si = 0.f;
#pragma unroll
        for (int t = 0; t < CL; ++t) {
          pl[ng]       = f2bf(sr);     // local prefix BEFORE step t
          pl[NST + ng] = f2bf(si);
          float nr = lr*sr - li*si + rr[t];
          float ni = lr*si + li*sr + ri[t];
          sr = nr; si = ni; pl += NPRE;
        }
        int c = cbase + buf*2 + p;
        int idx = (b*NC + c)*NST + ng;
        S_re[idx] = sr; S_im[idx] = si;
      }
    }
  }
}

// ---------------- two-level scan of chunk carries -> X0 --------------------
// level 1: carries over groups of 16 chunks. grid BATCH*8, block 256.
__global__ __launch_bounds__(256) void k_carry2(
    const float* __restrict__ S_re, const float* __restrict__ S_im,
    const float* __restrict__ lamre, const float* __restrict__ lamim,
    float* __restrict__ G_re, float* __restrict__ G_im) {
  int blk = blockIdx.x;
  int b = blk >> 3, g = blk & 7;
  int n = threadIdx.x;
  float ar = lamre[n], ai = lamim[n];
#pragma unroll
  for (int s = 0; s < 5; ++s) { float nr = ar*ar - ai*ai, ni = 2.f*ar*ai; ar = nr; ai = ni; } // lam^32
  float tr = 0.f, ti = 0.f;
#pragma unroll
  for (int cc = 0; cc < 16; ++cc) {
    int idx = (b*NC + g*16 + cc)*NST + n;
    float nr = ar*tr - ai*ti + S_re[idx];
    float ni = ar*ti + ai*tr + S_im[idx];
    tr = nr; ti = ni;
  }
  int gi = (b*8 + g)*NST + n;
  G_re[gi] = tr; G_im[gi] = ti;
}

// level 2: group prefix then per-chunk X0 (packed bf16). grid BATCH*8.
__global__ __launch_bounds__(256) void k_final(
    const float* __restrict__ S_re, const float* __restrict__ S_im,
    const float* __restrict__ G_re, const float* __restrict__ G_im,
    const float* __restrict__ lamre, const float* __restrict__ lamim,
    unsigned* __restrict__ X0Pk) {
  int blk = blockIdx.x;
  int b = blk >> 3, g = blk & 7;
  int n = threadIdx.x;
  float ar = lamre[n], ai = lamim[n];
#pragma unroll
  for (int s = 0; s < 5; ++s) { float nr = ar*ar - ai*ai, ni = 2.f*ar*ai; ar = nr; ai = ni; } // lam^32
  float a5r = ar, a5i = ai;
#pragma unroll
  for (int s = 0; s < 4; ++s) { float nr = a5r*a5r - a5i*a5i, ni = 2.f*a5r*a5i; a5r = nr; a5i = ni; } // lam^512
  float pr = 0.f, pi = 0.f;
  for (int j = 0; j < g; ++j) {
    int gi = (b*8 + j)*NST + n;
    float nr = a5r*pr - a5i*pi + G_re[gi];
    float ni = a5r*pi + a5i*pr + G_im[gi];
    pr = nr; pi = ni;
  }
  float xr = pr, xi = pi;
#pragma unroll
  for (int cc = 0; cc < 16; ++cc) {
    int idx = (b*NC + g*16 + cc)*NST + n;
    X0Pk[idx] = ((unsigned)f2bf(xi) << 16) | (unsigned)f2bf(xr);
    float nr = ar*xr - ai*xi + S_re[idx];
    float ni = ar*xi + ai*xr + S_im[idx];
    xr = nr; xi = ni;
  }
}

// ------- output GEMM: A-fragments direct from global + in-reg fix-up -------
// y[128 rows][128 o] = [fix(preL) | u] @ W^T.
// fix: pre[row][n] = preL[row][n] + lam^j * X0[chunk(row)][n], j = row & 31.
// Wave wid owns rows [wid*32, wid*32+32). Only B staged in LDS.
__global__ __launch_bounds__(256) void k_out2(
    const unsigned short* __restrict__ preL, const float* __restrict__ u,
    const unsigned short* __restrict__ W,
    const unsigned* __restrict__ lamPk, const unsigned* __restrict__ X0Pk,
    float* __restrict__ y) {
  __shared__ unsigned short Bsl[128][136];
  int tid = threadIdx.x;
  int row0 = blockIdx.x * 128;
  int wid = tid >> 6, lane = tid & 63;
  int lm = lane & 15, lq = lane >> 4;
  int m0 = wid * 32;
  f32x4 acc[2][8];
#pragma unroll
  for (int i = 0; i < 2; ++i)
#pragma unroll
    for (int j = 0; j < 8; ++j) acc[i][j] = (f32x4)0.f;
  int grow[2];
  grow[0] = row0 + m0 + lm;
  grow[1] = grow[0] + 16;
  for (int s = 0; s < 5; ++s) {
    // stage B: W[:, s*128 .. s*128+128)
#pragma unroll
    for (int cc = 0; cc < 8; ++cc) {
      int ch = cc*256 + tid;
      int r = ch >> 4, h0 = (ch & 15) * 8;
      *(short8*)&Bsl[r][h0] = *(const short8*)&W[(size_t)r*KTOT + s*128 + h0];
    }
    __syncthreads();
#pragma unroll
    for (int ks = 0; ks < 4; ++ks) {
      int k0 = ks*32 + lq*8;
      short8 a[2];
      if (s < 4) {
        int n = ((s & 1) << 7) + k0;
#pragma unroll
        for (int i = 0; i < 2; ++i) {
          int gr = grow[i];
          int j32 = gr & 31, cidx = gr >> 5;
          short8 loc = *(const short8*)&preL[(size_t)gr*NPRE + s*128 + k0];
          uint4 lp0 = *(const uint4*)&lamPk[j32*NST + n];
          uint4 lp1 = *(const uint4*)&lamPk[j32*NST + n + 4];
          uint4 xp0 = *(const uint4*)&X0Pk[cidx*NST + n];
          uint4 xp1 = *(const uint4*)&X0Pk[cidx*NST + n + 4];
          unsigned lps[8] = {lp0.x, lp0.y, lp0.z, lp0.w, lp1.x, lp1.y, lp1.z, lp1.w};
          unsigned xps[8] = {xp0.x, xp0.y, xp0.z, xp0.w, xp1.x, xp1.y, xp1.z, xp1.w};
          unsigned short o[8];
#pragma unroll
          for (int e = 0; e < 8; ++e) {
            float lr = bits2f(lps[e] << 16);
            float li = bits2f(lps[e] & 0xFFFF0000u);
            float xr = bits2f(xps[e] << 16);
            float xi = bits2f(xps[e] & 0xFFFF0000u);
            float lv = bf2f((unsigned short)loc[e]);
            float v = (s < 2) ? (lv + lr*xr - li*xi)
                              : (lv + lr*xi + li*xr);
            o[e] = f2bf(v);
          }
          a[i] = *(const short8*)o;
        }
      } else {
#pragma unroll
        for (int i = 0; i < 2; ++i) {
          const float* src = u + (size_t)grow[i]*HIN + k0;
          float4 v0 = *(const float4*)src;
          float4 v1 = *(const float4*)(src + 4);
          unsigned short o[8];
          o[0]=f2bf(v0.x); o[1]=f2bf(v0.y); o[2]=f2bf(v0.z); o[3]=f2bf(v0.w);
          o[4]=f2bf(v1.x); o[5]=f2bf(v1.y); o[6]=f2bf(v1.z); o[7]=f2bf(v1.w);
          a[i] = *(const short8*)o;
        }
      }
      short8 bb[8];
#pragma unroll
      for (int j = 0; j < 8; ++j) bb[j] = *(const short8*)&Bsl[j*16 + lm][k0];
#pragma unroll
      for (int i = 0; i < 2; ++i)
#pragma unroll
        for (int j = 0; j < 8; ++j)
          acc[i][j] = __builtin_amdgcn_mfma_f32_16x16x32_bf16(a[i], bb[j], acc[i][j], 0, 0, 0);
    }
    __syncthreads();
  }
#pragma unroll
  for (int i = 0; i < 2; ++i)
#pragma unroll
    for (int j = 0; j < 8; ++j)
#pragma unroll
      for (int r = 0; r < 4; ++r)
        y[(size_t)(row0 + m0 + i*16 + lq*4 + r)*HOUT + j*16 + lm] = acc[i][j][r];
}

// --------------------------------------------------------------------------
extern "C" void kernel_launch(void* const* d_in, const int* in_sizes, int n_in,
                              void* d_out, int out_size, void* d_ws, size_t ws_size,
                              hipStream_t stream) {
  const float* u         = (const float*)d_in[0];
  const float* nu_log    = (const float*)d_in[1];
  const float* theta_log = (const float*)d_in[2];
  const float* gamma_log = (const float*)d_in[3];
  const float* B_re      = (const float*)d_in[4];
  const float* B_im      = (const float*)d_in[5];
  const float* C_re      = (const float*)d_in[6];
  const float* C_im      = (const float*)d_in[7];
  const float* Dm        = (const float*)d_in[8];
  float* y = (float*)d_out;
  char* ws = (char*)d_ws;

  size_t off = 0;
  float* lamre = (float*)(ws + off);            off += 1024;
  float* lamim = (float*)(ws + off);            off += 1024;
  unsigned* lamPk = (unsigned*)(ws + off);      off += 32768;       // 32x256 u32
  unsigned short* Wb = (unsigned short*)(ws + off); off += 131072;  // 512x128 bf16
  unsigned short* W  = (unsigned short*)(ws + off); off += 163840;  // 128x640 bf16
  unsigned short* preL = (unsigned short*)(ws + off); off += (size_t)ROWS*NPRE*2; // 64 MB
  float* S_re = (float*)(ws + off);             off += 2097152;
  float* S_im = (float*)(ws + off);             off += 2097152;
  float* G_re = (float*)(ws + off);             off += 131072;
  float* G_im = (float*)(ws + off);             off += 131072;
  unsigned* X0Pk = (unsigned*)(ws + off);       off += 2097152;     // 2048x256 u32

  k_prep<<<320, 256, 0, stream>>>(nu_log, theta_log, gamma_log, B_re, B_im,
                                  C_re, C_im, Dm, lamre, lamim, lamPk, Wb, W);
  k_bu<<<ROWS/128, 256, 0, stream>>>(u, Wb, lamre, lamim, preL, S_re, S_im);
  k_carry2<<<BATCH*8, 256, 0, stream>>>(S_re, S_im, lamre, lamim, G_re, G_im);
  k_final<<<BATCH*8, 256, 0, stream>>>(S_re, S_im, G_re, G_im, lamre, lamim, X0Pk);
  k_out2<<<ROWS/128, 256, 0, stream>>>(preL, u, W, lamPk, X0Pk, y);
}